// Round 1
// baseline (3387.733 us; speedup 1.0000x reference)
//
#include <hip/hip_runtime.h>
#include <hip/hip_bf16.h>
#include <math.h>

#define NB 32768
#define NTOK (3 * NB)
#define NNODES 20000
#define TPB 4
#define MAXL 256

// ---------------- helpers ----------------

__device__ __forceinline__ float block_sum(float v, float* red) {
    int d = threadIdx.x;
    red[d] = v;
    __syncthreads();
#pragma unroll
    for (int s = 64; s > 0; s >>= 1) {
        if (d < s) red[d] += red[d + s];
        __syncthreads();
    }
    float r = red[0];
    __syncthreads();
    return r;
}

__device__ __forceinline__ int self_node(int t, const int* src, const int* dst, const int* neg) {
    if (t < NB) return src[t];
    if (t < 2 * NB) return dst[t - NB];
    return neg[t - 2 * NB];
}

// ---------------- setup kernels ----------------

// out[c*R + r] = in[r*C + c]   (in is R rows x C cols, row-major)
__global__ void transpose_k(const float* __restrict__ in, float* __restrict__ out, int R, int C) {
    int idx = blockIdx.x * 256 + threadIdx.x;
    if (idx < R * C) {
        int r = idx / C, c = idx % C;
        out[c * R + r] = in[r * C + c];
    }
}

__global__ void count_k(const int* __restrict__ src, const int* __restrict__ dst,
                        const int* __restrict__ neg, int* __restrict__ cnt) {
    int t = blockIdx.x * 256 + threadIdx.x;
    if (t >= NTOK) return;
    atomicAdd(&cnt[self_node(t, src, dst, neg)], 1);
}

__global__ void scan_k(const int* __restrict__ cnt, int* __restrict__ starts, int n) {
    __shared__ int buf[256];
    __shared__ int carry;
    int d = threadIdx.x;
    if (d == 0) carry = 0;
    __syncthreads();
    for (int base = 0; base < n; base += 256) {
        int i = base + d;
        int v = (i < n) ? cnt[i] : 0;
        buf[d] = v;
        __syncthreads();
        for (int off = 1; off < 256; off <<= 1) {
            int t = (d >= off) ? buf[d - off] : 0;
            __syncthreads();
            buf[d] += t;
            __syncthreads();
        }
        if (i < n) starts[i] = carry + buf[d] - v;  // exclusive
        __syncthreads();
        if (d == 255) carry += buf[255];
        __syncthreads();
    }
}

__global__ void scatter_k(const int* __restrict__ src, const int* __restrict__ dst,
                          const int* __restrict__ neg, const int* __restrict__ starts,
                          int* __restrict__ cursor, int* __restrict__ order,
                          int* __restrict__ node_of) {
    int t = blockIdx.x * 256 + threadIdx.x;
    if (t >= NTOK) return;
    int node = self_node(t, src, dst, neg);
    node_of[t] = node;
    int p = atomicAdd(&cursor[node], 1);
    order[starts[node] + p] = t;
}

// ---------------- embedding ----------------

__global__ __launch_bounds__(128) void embed_k(
    const int* __restrict__ src, const int* __restrict__ dst, const int* __restrict__ neg,
    const int* __restrict__ eidx, const float* __restrict__ ts,
    const float* __restrict__ node_feats, const float* __restrict__ edge_feats,
    const float* __restrict__ nlT, const float* __restrict__ nl_b,
    const float* __restrict__ elT, const float* __restrict__ el_b,
    const float* __restrict__ time_w, const float* __restrict__ time_b,
    const float* __restrict__ tokT, const float* __restrict__ tok_b,
    float* __restrict__ x) {
    __shared__ float sf[TPB][128];
    __shared__ float of[TPB][128];
    __shared__ float ef[TPB][64];
    __shared__ float xcat[TPB][512];
    int d = threadIdx.x;
    int base = blockIdx.x * TPB;

    float tsv[TPB];
#pragma unroll
    for (int tt = 0; tt < TPB; ++tt) {
        int t = base + tt;
        int sN, oN;
        if (t < NB) { sN = src[t]; oN = dst[t]; }
        else if (t < 2 * NB) { sN = dst[t - NB]; oN = src[t - NB]; }
        else { sN = neg[t - 2 * NB]; oN = src[t - 2 * NB]; }
        int m = (t < NB) ? t : ((t < 2 * NB) ? t - NB : t - 2 * NB);
        int e = eidx[m];
        tsv[tt] = ts[m];
        sf[tt][d] = node_feats[sN * 128 + d];
        of[tt][d] = node_feats[oN * 128 + d];
        if (d < 64) ef[tt][d] = edge_feats[e * 64 + d];
    }
    __syncthreads();

    float bs[TPB], bo[TPB], ee[TPB];
#pragma unroll
    for (int tt = 0; tt < TPB; ++tt) { bs[tt] = nl_b[d]; bo[tt] = nl_b[d]; ee[tt] = el_b[d]; }
    for (int f = 0; f < 128; ++f) {
        float w = nlT[f * 128 + d];
#pragma unroll
        for (int tt = 0; tt < TPB; ++tt) { bs[tt] += sf[tt][f] * w; bo[tt] += of[tt][f] * w; }
    }
    for (int f = 0; f < 64; ++f) {
        float w = elT[f * 128 + d];
#pragma unroll
        for (int tt = 0; tt < TPB; ++tt) ee[tt] += ef[tt][f] * w;
    }
    float tw = time_w[d], tb = time_b[d];
#pragma unroll
    for (int tt = 0; tt < TPB; ++tt) {
        xcat[tt][d] = bs[tt];
        xcat[tt][128 + d] = bo[tt];
        xcat[tt][256 + d] = ee[tt];
        xcat[tt][384 + d] = cosf(tsv[tt] * tw + tb);
    }
    __syncthreads();

    float acc[TPB];
#pragma unroll
    for (int tt = 0; tt < TPB; ++tt) acc[tt] = tok_b[d];
    for (int j = 0; j < 512; ++j) {
        float w = tokT[j * 128 + d];
#pragma unroll
        for (int tt = 0; tt < TPB; ++tt) acc[tt] += xcat[tt][j] * w;
    }
#pragma unroll
    for (int tt = 0; tt < TPB; ++tt) x[(base + tt) * 128 + d] = fmaxf(acc[tt], 0.f);
}

// ---------------- LN1 + QKV ----------------

__global__ __launch_bounds__(128) void qkv_k(
    const float* __restrict__ x, const float* __restrict__ qkvT, const float* __restrict__ qkv_b,
    const float* __restrict__ s1, const float* __restrict__ b1,
    float* __restrict__ q, float* __restrict__ k, float* __restrict__ v) {
    __shared__ float hl[TPB][128];
    __shared__ float red[128];
    int d = threadIdx.x;
    int base = blockIdx.x * TPB;
#pragma unroll
    for (int tt = 0; tt < TPB; ++tt) {
        float xv = x[(base + tt) * 128 + d];
        float m = block_sum(xv, red) * (1.f / 128.f);
        float c = xv - m;
        float var = block_sum(c * c, red) * (1.f / 128.f);
        hl[tt][d] = c * rsqrtf(var + 1e-5f) * s1[d] + b1[d];
    }
    __syncthreads();
    float aq[TPB], ak[TPB], av[TPB];
#pragma unroll
    for (int tt = 0; tt < TPB; ++tt) {
        aq[tt] = qkv_b[d]; ak[tt] = qkv_b[128 + d]; av[tt] = qkv_b[256 + d];
    }
    for (int f = 0; f < 128; ++f) {
        float w0 = qkvT[f * 384 + d];
        float w1 = qkvT[f * 384 + 128 + d];
        float w2 = qkvT[f * 384 + 256 + d];
#pragma unroll
        for (int tt = 0; tt < TPB; ++tt) {
            float hf = hl[tt][f];
            aq[tt] += hf * w0; ak[tt] += hf * w1; av[tt] += hf * w2;
        }
    }
#pragma unroll
    for (int tt = 0; tt < TPB; ++tt) {
        int t = base + tt;
        q[t * 128 + d] = aq[tt];
        k[t * 128 + d] = ak[tt];
        v[t * 128 + d] = av[tt];
    }
}

// ---------------- attention (one token per block) ----------------

__global__ __launch_bounds__(128) void attn_k(
    const float* __restrict__ q, const float* __restrict__ k, const float* __restrict__ v,
    const int* __restrict__ node_of, const int* __restrict__ starts, const int* __restrict__ cnt,
    const int* __restrict__ order, const float* __restrict__ attnT,
    const float* __restrict__ attn_b, float* __restrict__ x) {
    __shared__ float sc[4][MAXL];
    __shared__ int keys[MAXL];
    __shared__ float ol[128];
    __shared__ float sinv[4];
    int t = blockIdx.x, d = threadIdx.x;
    int node = node_of[t];
    int st = starts[node];
    int len = cnt[node];
    if (len > MAXL) len = MAXL;
    for (int j = d; j < len; j += 128) keys[j] = order[st + j];
    float qv = q[t * 128 + d];
    __syncthreads();
    int h = d >> 5, lane = d & 31;
    const float scale = 0.17677669529663687f;  // 1/sqrt(32)
    for (int j = 0; j < len; ++j) {
        int key = keys[j];
        float p = qv * k[key * 128 + d];
#pragma unroll
        for (int off = 16; off; off >>= 1) p += __shfl_xor(p, off, 64);
        if (lane == 0) sc[h][j] = p * scale;
    }
    __syncthreads();
    {
        float mx = -1e30f;
        for (int j = lane; j < len; j += 32) mx = fmaxf(mx, sc[h][j]);
#pragma unroll
        for (int off = 16; off; off >>= 1) mx = fmaxf(mx, __shfl_xor(mx, off, 64));
        float s = 0.f;
        for (int j = lane; j < len; j += 32) {
            float e = expf(sc[h][j] - mx);
            sc[h][j] = e;
            s += e;
        }
#pragma unroll
        for (int off = 16; off; off >>= 1) s += __shfl_xor(s, off, 64);
        if (lane == 0) sinv[h] = 1.f / s;
    }
    __syncthreads();
    float acc = 0.f;
    for (int j = 0; j < len; ++j) acc += sc[h][j] * v[keys[j] * 128 + d];
    ol[d] = acc * sinv[h];
    __syncthreads();
    float o2 = attn_b[d];
    for (int f = 0; f < 128; ++f) o2 += ol[f] * attnT[f * 128 + d];
    x[t * 128 + d] += o2;
}

// ---------------- LN2 + FFN ----------------

__global__ __launch_bounds__(128) void ff_k(
    float* __restrict__ x, const float* __restrict__ ff1T, const float* __restrict__ ff1_b,
    const float* __restrict__ ff2T, const float* __restrict__ ff2_b,
    const float* __restrict__ s2, const float* __restrict__ b2) {
    __shared__ float hl[TPB][128];
    __shared__ float ul[TPB][512];
    __shared__ float red[128];
    int d = threadIdx.x;
    int base = blockIdx.x * TPB;
#pragma unroll
    for (int tt = 0; tt < TPB; ++tt) {
        float xv = x[(base + tt) * 128 + d];
        float m = block_sum(xv, red) * (1.f / 128.f);
        float c = xv - m;
        float var = block_sum(c * c, red) * (1.f / 128.f);
        hl[tt][d] = c * rsqrtf(var + 1e-5f) * s2[d] + b2[d];
    }
    __syncthreads();
    float u0[TPB], u1[TPB], u2[TPB], u3[TPB];
#pragma unroll
    for (int tt = 0; tt < TPB; ++tt) {
        u0[tt] = ff1_b[d]; u1[tt] = ff1_b[128 + d]; u2[tt] = ff1_b[256 + d]; u3[tt] = ff1_b[384 + d];
    }
    for (int f = 0; f < 128; ++f) {
        float w0 = ff1T[f * 512 + d];
        float w1 = ff1T[f * 512 + 128 + d];
        float w2 = ff1T[f * 512 + 256 + d];
        float w3 = ff1T[f * 512 + 384 + d];
#pragma unroll
        for (int tt = 0; tt < TPB; ++tt) {
            float hf = hl[tt][f];
            u0[tt] += hf * w0; u1[tt] += hf * w1; u2[tt] += hf * w2; u3[tt] += hf * w3;
        }
    }
    const float is2 = 0.7071067811865476f;
#pragma unroll
    for (int tt = 0; tt < TPB; ++tt) {
        float a;
        a = u0[tt]; ul[tt][d] = 0.5f * a * (1.f + erff(a * is2));
        a = u1[tt]; ul[tt][128 + d] = 0.5f * a * (1.f + erff(a * is2));
        a = u2[tt]; ul[tt][256 + d] = 0.5f * a * (1.f + erff(a * is2));
        a = u3[tt]; ul[tt][384 + d] = 0.5f * a * (1.f + erff(a * is2));
    }
    __syncthreads();
    float acc[TPB];
#pragma unroll
    for (int tt = 0; tt < TPB; ++tt) acc[tt] = ff2_b[d];
    for (int j = 0; j < 512; ++j) {
        float w = ff2T[j * 128 + d];
#pragma unroll
        for (int tt = 0; tt < TPB; ++tt) acc[tt] += ul[tt][j] * w;
    }
#pragma unroll
    for (int tt = 0; tt < TPB; ++tt) x[(base + tt) * 128 + d] += acc[tt];
}

// ---------------- final projection head ----------------

__global__ __launch_bounds__(128) void proj_k(
    const float* __restrict__ x, const float* __restrict__ p1T, const float* __restrict__ p1_b,
    const float* __restrict__ p2_w, const float* __restrict__ p2_b, float* __restrict__ out) {
    __shared__ float hl[TPB][128];
    __shared__ float red[128];
    __shared__ float lg[TPB][5];
    int d = threadIdx.x;
    int base = blockIdx.x * TPB;
#pragma unroll
    for (int tt = 0; tt < TPB; ++tt) hl[tt][d] = x[(base + tt) * 128 + d];
    __syncthreads();
    float r[TPB];
#pragma unroll
    for (int tt = 0; tt < TPB; ++tt) r[tt] = p1_b[d];
    for (int f = 0; f < 128; ++f) {
        float w = p1T[f * 128 + d];
#pragma unroll
        for (int tt = 0; tt < TPB; ++tt) r[tt] += hl[tt][f] * w;
    }
#pragma unroll
    for (int tt = 0; tt < TPB; ++tt) r[tt] = fmaxf(r[tt], 0.f);
    for (int kk = 0; kk < 5; ++kk) {
        float w2 = p2_w[kk * 128 + d];
#pragma unroll
        for (int tt = 0; tt < TPB; ++tt) {
            float s = block_sum(r[tt] * w2, red);
            if (d == 0) lg[tt][kk] = s + p2_b[kk];
        }
    }
    __syncthreads();
    if (d < TPB) {
        int tt = d;
        float mx = -1e30f;
#pragma unroll
        for (int kk = 0; kk < 5; ++kk) mx = fmaxf(mx, lg[tt][kk]);
        float e[5], s = 0.f;
#pragma unroll
        for (int kk = 0; kk < 5; ++kk) { e[kk] = expf(lg[tt][kk] - mx); s += e[kk]; }
#pragma unroll
        for (int kk = 0; kk < 5; ++kk) out[(base + tt) * 5 + kk] = e[kk] / s;
    }
}

// ---------------- host launch ----------------

extern "C" void kernel_launch(void* const* d_in, const int* in_sizes, int n_in,
                              void* d_out, int out_size, void* d_ws, size_t ws_size,
                              hipStream_t stream) {
    const int* src = (const int*)d_in[0];
    const int* dst = (const int*)d_in[1];
    const int* neg = (const int*)d_in[2];
    const int* eidx = (const int*)d_in[3];
    const float* ts = (const float*)d_in[4];
    const float* node_feats = (const float*)d_in[5];
    const float* edge_feats = (const float*)d_in[6];
    const float* node_lin_w = (const float*)d_in[7];
    const float* node_lin_b = (const float*)d_in[8];
    const float* edge_lin_w = (const float*)d_in[9];
    const float* edge_lin_b = (const float*)d_in[10];
    const float* time_w = (const float*)d_in[11];
    const float* time_b = (const float*)d_in[12];
    const float* tok_w = (const float*)d_in[13];
    const float* tok_b = (const float*)d_in[14];
    const float* qkv_w = (const float*)d_in[15];
    const float* qkv_b = (const float*)d_in[16];
    const float* attn_w = (const float*)d_in[17];
    const float* attn_b = (const float*)d_in[18];
    const float* ln1_s = (const float*)d_in[19];
    const float* ln1_b = (const float*)d_in[20];
    const float* ln2_s = (const float*)d_in[21];
    const float* ln2_b = (const float*)d_in[22];
    const float* ff1_w = (const float*)d_in[23];
    const float* ff1_b = (const float*)d_in[24];
    const float* ff2_w = (const float*)d_in[25];
    const float* ff2_b = (const float*)d_in[26];
    const float* p1_w = (const float*)d_in[27];
    const float* p1_b = (const float*)d_in[28];
    const float* p2_w = (const float*)d_in[29];
    const float* p2_b = (const float*)d_in[30];
    float* out = (float*)d_out;

    char* w = (char*)d_ws;
    auto alloc = [&](size_t bytes) {
        char* p = w;
        w += (bytes + 255) & ~(size_t)255;
        return p;
    };
    float* x = (float*)alloc((size_t)NTOK * 128 * 4);
    float* qb = (float*)alloc((size_t)NTOK * 128 * 4);
    float* kb = (float*)alloc((size_t)NTOK * 128 * 4);
    float* vb = (float*)alloc((size_t)NTOK * 128 * 4);
    int* cnt = (int*)alloc(NNODES * 4);
    int* starts = (int*)alloc(NNODES * 4);
    int* cursor = (int*)alloc(NNODES * 4);
    int* order = (int*)alloc(NTOK * 4);
    int* node_of = (int*)alloc(NTOK * 4);
    float* nlT = (float*)alloc(128 * 128 * 4);
    float* elT = (float*)alloc(64 * 128 * 4);
    float* tokT = (float*)alloc(512 * 128 * 4);
    float* qkvT = (float*)alloc(2 * 128 * 384 * 4);
    float* attnT = (float*)alloc(2 * 128 * 128 * 4);
    float* ff1T = (float*)alloc(2 * 128 * 512 * 4);
    float* ff2T = (float*)alloc(2 * 512 * 128 * 4);
    float* p1T = (float*)alloc(128 * 128 * 4);

    hipMemsetAsync(cnt, 0, NNODES * 4, stream);
    hipMemsetAsync(cursor, 0, NNODES * 4, stream);

    auto tr = [&](const float* in, float* outp, int R, int C) {
        int n = R * C;
        transpose_k<<<(n + 255) / 256, 256, 0, stream>>>(in, outp, R, C);
    };
    tr(node_lin_w, nlT, 128, 128);
    tr(edge_lin_w, elT, 128, 64);
    tr(tok_w, tokT, 128, 512);
    for (int l = 0; l < 2; ++l) {
        tr(qkv_w + l * 384 * 128, qkvT + l * 128 * 384, 384, 128);
        tr(attn_w + l * 128 * 128, attnT + l * 128 * 128, 128, 128);
        tr(ff1_w + l * 512 * 128, ff1T + l * 128 * 512, 512, 128);
        tr(ff2_w + l * 128 * 512, ff2T + l * 512 * 128, 128, 512);
    }
    tr(p1_w, p1T, 128, 128);

    count_k<<<(NTOK + 255) / 256, 256, 0, stream>>>(src, dst, neg, cnt);
    scan_k<<<1, 256, 0, stream>>>(cnt, starts, NNODES);
    scatter_k<<<(NTOK + 255) / 256, 256, 0, stream>>>(src, dst, neg, starts, cursor, order, node_of);

    embed_k<<<NTOK / TPB, 128, 0, stream>>>(src, dst, neg, eidx, ts, node_feats, edge_feats,
                                            nlT, node_lin_b, elT, edge_lin_b, time_w, time_b,
                                            tokT, tok_b, x);

    for (int l = 0; l < 2; ++l) {
        qkv_k<<<NTOK / TPB, 128, 0, stream>>>(x, qkvT + l * 128 * 384, qkv_b + l * 384,
                                              ln1_s + l * 128, ln1_b + l * 128, qb, kb, vb);
        attn_k<<<NTOK, 128, 0, stream>>>(qb, kb, vb, node_of, starts, cnt, order,
                                         attnT + l * 128 * 128, attn_b + l * 128, x);
        ff_k<<<NTOK / TPB, 128, 0, stream>>>(x, ff1T + l * 128 * 512, ff1_b + l * 512,
                                             ff2T + l * 512 * 128, ff2_b + l * 128,
                                             ln2_s + l * 128, ln2_b + l * 128);
    }

    proj_k<<<NTOK / TPB, 128, 0, stream>>>(x, p1T, p1_b, p2_w, p2_b, out);
}

// Round 2
// 1123.506 us; speedup vs baseline: 3.0153x; 3.0153x over previous
//
#include <hip/hip_runtime.h>
#include <hip/hip_bf16.h>
#include <math.h>

#define NB 32768
#define NTOK (3 * NB)
#define NNODES 20000
#define MAXL 256

typedef short bf16x8 __attribute__((ext_vector_type(8)));
typedef float f32x4 __attribute__((ext_vector_type(4)));

// ---------------- small setup kernels ----------------

__global__ void convert_k(const float* __restrict__ in, __hip_bfloat16* __restrict__ out, int n) {
    int i = blockIdx.x * 256 + threadIdx.x;
    int stride = gridDim.x * 256;
    for (; i < n; i += stride) out[i] = __float2bfloat16(in[i]);
}

// A12[n][f], n in [0,256): n<128: sum_c tok_w[n*512+c]*nl_w[c*128+f]
//                          n>=128: sum_c tok_w[(n-128)*512+128+c]*nl_w[c*128+f]
__global__ void fold12_k(const float* __restrict__ tok_w, const float* __restrict__ nl_w,
                         __hip_bfloat16* __restrict__ A12) {
    int idx = blockIdx.x * 256 + threadIdx.x;
    if (idx >= 256 * 128) return;
    int n = idx >> 7, f = idx & 127;
    const float* tw = (n < 128) ? (tok_w + n * 512) : (tok_w + (n - 128) * 512 + 128);
    float acc = 0.f;
    for (int c = 0; c < 128; ++c) acc += tw[c] * nl_w[c * 128 + f];
    A12[idx] = __float2bfloat16(acc);
}

// AE[d][j], j<64: sum_c tok_w[d*512+256+c]*el_w[c*64+j]; j>=64: tok_w[d*512+384+(j-64)]
__global__ void foldE_k(const float* __restrict__ tok_w, const float* __restrict__ el_w,
                        __hip_bfloat16* __restrict__ AE) {
    int idx = blockIdx.x * 256 + threadIdx.x;
    if (idx >= 128 * 192) return;
    int d = idx / 192, j = idx % 192;
    float acc;
    if (j < 64) {
        acc = 0.f;
        for (int c = 0; c < 128; ++c) acc += tok_w[d * 512 + 256 + c] * el_w[c * 64 + j];
    } else {
        acc = tok_w[d * 512 + 384 + (j - 64)];
    }
    AE[idx] = __float2bfloat16(acc);
}

__global__ void foldb_k(const float* __restrict__ tok_w, const float* __restrict__ tok_b,
                        const float* __restrict__ nl_b, const float* __restrict__ el_b,
                        float* __restrict__ bf) {
    int d = threadIdx.x;
    if (d >= 128) return;
    float acc = tok_b[d];
    for (int c = 0; c < 128; ++c)
        acc += (tok_w[d * 512 + c] + tok_w[d * 512 + 128 + c]) * nl_b[c];
    for (int c = 0; c < 128; ++c)
        acc += tok_w[d * 512 + 256 + c] * el_b[c];
    bf[d] = acc;
}

__device__ __forceinline__ int self_node(int t, const int* src, const int* dst, const int* neg) {
    if (t < NB) return src[t];
    if (t < 2 * NB) return dst[t - NB];
    return neg[t - 2 * NB];
}

__global__ void count_k(const int* __restrict__ src, const int* __restrict__ dst,
                        const int* __restrict__ neg, int* __restrict__ cnt) {
    int t = blockIdx.x * 256 + threadIdx.x;
    if (t >= NTOK) return;
    atomicAdd(&cnt[self_node(t, src, dst, neg)], 1);
}

__global__ void scan_k(const int* __restrict__ cnt, int* __restrict__ starts, int n) {
    __shared__ int buf[256];
    __shared__ int carry;
    int d = threadIdx.x;
    if (d == 0) carry = 0;
    __syncthreads();
    for (int base = 0; base < n; base += 256) {
        int i = base + d;
        int v = (i < n) ? cnt[i] : 0;
        buf[d] = v;
        __syncthreads();
        for (int off = 1; off < 256; off <<= 1) {
            int t = (d >= off) ? buf[d - off] : 0;
            __syncthreads();
            buf[d] += t;
            __syncthreads();
        }
        if (i < n) starts[i] = carry + buf[d] - v;
        __syncthreads();
        if (d == 255) carry += buf[255];
        __syncthreads();
    }
}

__global__ void scatter_k(const int* __restrict__ src, const int* __restrict__ dst,
                          const int* __restrict__ neg, const int* __restrict__ starts,
                          int* __restrict__ cursor, int* __restrict__ order,
                          int* __restrict__ node_of) {
    int t = blockIdx.x * 256 + threadIdx.x;
    if (t >= NTOK) return;
    int node = self_node(t, src, dst, neg);
    node_of[t] = node;
    int p = atomicAdd(&cursor[node], 1);
    order[starts[node] + p] = t;
}

// Aemb[m][0:64] = edge_feats[eidx[m]]; Aemb[m][64+c] = cos(ts[m]*tw[c]+tb[c])
__global__ void aemb_k(const int* __restrict__ eidx, const float* __restrict__ ts,
                       const float* __restrict__ ef, const float* __restrict__ tw,
                       const float* __restrict__ tb, __hip_bfloat16* __restrict__ Aemb) {
    int idx = blockIdx.x * 256 + threadIdx.x;
    if (idx >= NB * 192) return;
    int m = idx / 192, j = idx % 192;
    float v;
    if (j < 64) v = ef[(size_t)eidx[m] * 64 + j];
    else { int c = j - 64; v = cosf(ts[m] * tw[c] + tb[c]); }
    Aemb[idx] = __float2bfloat16(v);
}

// x[t] = relu(P12[self][0:128] + P12[other][128:256] + E[m])
__global__ __launch_bounds__(256) void asm_k(
    const int* __restrict__ src, const int* __restrict__ dst, const int* __restrict__ neg,
    const float* __restrict__ P12, const float* __restrict__ E, float* __restrict__ x) {
    int t = blockIdx.x * 2 + (threadIdx.x >> 7);
    int d = threadIdx.x & 127;
    int m, self, other;
    if (t < NB) { m = t; self = src[m]; other = dst[m]; }
    else if (t < 2 * NB) { m = t - NB; self = dst[m]; other = src[m]; }
    else { m = t - 2 * NB; self = neg[m]; other = src[m]; }
    float v = P12[(size_t)self * 256 + d] + P12[(size_t)other * 256 + 128 + d] +
              E[(size_t)m * 128 + d];
    x[(size_t)t * 128 + d] = fmaxf(v, 0.f);
}

// ---------------- MFMA GEMM ----------------
// C[M][N] = A[M][K] @ B[N][K]^T (+bias). A,B bf16, acc fp32.
// tiles: 128x128, BK=64, 4 waves (each 64x64 via 4x4 16x16x32 frags).
#define MODE_F32 0
#define MODE_BF16 1
#define MODE_RELU_BF16 2
#define MODE_GELU_BF16 3
#define MODE_ADD 4
#define MODE_ADD_BF16 5

template <int MODE>
__global__ __launch_bounds__(256) void gemm_k(
    const __hip_bfloat16* __restrict__ A, const __hip_bfloat16* __restrict__ B,
    const float* __restrict__ bias, float* __restrict__ Cf,
    __hip_bfloat16* __restrict__ Cb, int M, int N, int K) {
    __shared__ float4 As4[1024];
    __shared__ float4 Bs4[1024];
    int tid = threadIdx.x;
    int lane = tid & 63, wid = tid >> 6;
    int wm = wid & 1, wn = wid >> 1;
    int mBase = blockIdx.x * 128, nBase = blockIdx.y * 128;
    const float4 fzero = {0.f, 0.f, 0.f, 0.f};
    f32x4 acc[4][4];
#pragma unroll
    for (int i = 0; i < 4; ++i)
#pragma unroll
        for (int j = 0; j < 4; ++j) {
            f32x4 z = {0.f, 0.f, 0.f, 0.f};
            acc[i][j] = z;
        }
    bf16x8* AsV = reinterpret_cast<bf16x8*>(As4);
    bf16x8* BsV = reinterpret_cast<bf16x8*>(Bs4);

    for (int k0 = 0; k0 < K; k0 += 64) {
#pragma unroll
        for (int i = 0; i < 4; ++i) {
            int cid = i * 256 + tid;
            int r = cid >> 3, c = cid & 7;
            int sidx = r * 8 + (c ^ (r & 7));
            int gr = mBase + r;
            float4 va = fzero;
            if (gr < M)
                va = *reinterpret_cast<const float4*>(A + (size_t)gr * K + k0 + c * 8);
            As4[sidx] = va;
            int gn = nBase + r;
            Bs4[sidx] = *reinterpret_cast<const float4*>(B + (size_t)gn * K + k0 + c * 8);
        }
        __syncthreads();
#pragma unroll
        for (int kk = 0; kk < 2; ++kk) {
            bf16x8 a[4], b[4];
            int ccol = kk * 4 + (lane >> 4);
#pragma unroll
            for (int f = 0; f < 4; ++f) {
                int ra = wm * 64 + f * 16 + (lane & 15);
                a[f] = AsV[ra * 8 + (ccol ^ (ra & 7))];
                int rb = wn * 64 + f * 16 + (lane & 15);
                b[f] = BsV[rb * 8 + (ccol ^ (rb & 7))];
            }
#pragma unroll
            for (int fm = 0; fm < 4; ++fm)
#pragma unroll
                for (int fn = 0; fn < 4; ++fn)
                    acc[fm][fn] = __builtin_amdgcn_mfma_f32_16x16x32_bf16(
                        a[fm], b[fn], acc[fm][fn], 0, 0, 0);
        }
        __syncthreads();
    }

    int colBase = nBase + wn * 64;
#pragma unroll
    for (int fm = 0; fm < 4; ++fm) {
        int row0 = mBase + wm * 64 + fm * 16 + (lane >> 4) * 4;
#pragma unroll
        for (int fn = 0; fn < 4; ++fn) {
            int col = colBase + fn * 16 + (lane & 15);
            float bv = bias ? bias[col] : 0.f;
#pragma unroll
            for (int j = 0; j < 4; ++j) {
                int row = row0 + j;
                if (row >= M) continue;
                float v = acc[fm][fn][j] + bv;
                size_t off = (size_t)row * N + col;
                if (MODE == MODE_F32) {
                    Cf[off] = v;
                } else if (MODE == MODE_BF16) {
                    Cb[off] = __float2bfloat16(v);
                } else if (MODE == MODE_RELU_BF16) {
                    Cb[off] = __float2bfloat16(fmaxf(v, 0.f));
                } else if (MODE == MODE_GELU_BF16) {
                    Cb[off] = __float2bfloat16(0.5f * v * (1.f + erff(v * 0.70710678118f)));
                } else if (MODE == MODE_ADD) {
                    Cf[off] += v;
                } else {
                    float nv = Cf[off] + v;
                    Cf[off] = nv;
                    Cb[off] = __float2bfloat16(nv);
                }
            }
        }
    }
}

// ---------------- LayerNorm: x fp32 -> h bf16 ----------------
__global__ __launch_bounds__(256) void ln_k(const float* __restrict__ x,
                                            const float* __restrict__ s,
                                            const float* __restrict__ b,
                                            __hip_bfloat16* __restrict__ h) {
    int t = blockIdx.x * 4 + (threadIdx.x >> 6);
    int lane = threadIdx.x & 63;
    const float* xr = x + (size_t)t * 128;
    float v0 = xr[lane], v1 = xr[64 + lane];
    float sum = v0 + v1;
#pragma unroll
    for (int off = 32; off; off >>= 1) sum += __shfl_xor(sum, off, 64);
    float mean = sum * (1.f / 128.f);
    float c0 = v0 - mean, c1 = v1 - mean;
    float vs = c0 * c0 + c1 * c1;
#pragma unroll
    for (int off = 32; off; off >>= 1) vs += __shfl_xor(vs, off, 64);
    float inv = rsqrtf(vs * (1.f / 128.f) + 1e-5f);
    __hip_bfloat16* hr = h + (size_t)t * 128;
    hr[lane] = __float2bfloat16(c0 * inv * s[lane] + b[lane]);
    hr[64 + lane] = __float2bfloat16(c1 * inv * s[64 + lane] + b[64 + lane]);
}

// ---------------- attention over groups (qkv bf16 packed [t][384]) ----------------
__global__ __launch_bounds__(128) void attn_k(
    const __hip_bfloat16* __restrict__ qkv, const int* __restrict__ node_of,
    const int* __restrict__ starts, const int* __restrict__ cnt,
    const int* __restrict__ order, __hip_bfloat16* __restrict__ o) {
    __shared__ float sc[4][MAXL];
    __shared__ int keys[MAXL];
    __shared__ float sinv[4];
    int t = blockIdx.x, d = threadIdx.x;
    int node = node_of[t];
    int st = starts[node];
    int len = cnt[node];
    if (len > MAXL) len = MAXL;
    for (int j = d; j < len; j += 128) keys[j] = order[st + j];
    float qv = __bfloat162float(qkv[(size_t)t * 384 + d]);
    __syncthreads();
    int h = d >> 5, lane = d & 31;
    const float scale = 0.17677669529663687f;
    for (int j = 0; j < len; ++j) {
        float p = qv * __bfloat162float(qkv[(size_t)keys[j] * 384 + 128 + d]);
#pragma unroll
        for (int off = 16; off; off >>= 1) p += __shfl_xor(p, off, 64);
        if (lane == 0) sc[h][j] = p * scale;
    }
    __syncthreads();
    float mx = -1e30f;
    for (int j = lane; j < len; j += 32) mx = fmaxf(mx, sc[h][j]);
#pragma unroll
    for (int off = 16; off; off >>= 1) mx = fmaxf(mx, __shfl_xor(mx, off, 64));
    float ssum = 0.f;
    for (int j = lane; j < len; j += 32) {
        float e = expf(sc[h][j] - mx);
        sc[h][j] = e;
        ssum += e;
    }
#pragma unroll
    for (int off = 16; off; off >>= 1) ssum += __shfl_xor(ssum, off, 64);
    if (lane == 0) sinv[h] = 1.f / ssum;
    __syncthreads();
    float accv = 0.f;
    for (int j = 0; j < len; ++j)
        accv += sc[h][j] * __bfloat162float(qkv[(size_t)keys[j] * 384 + 256 + d]);
    o[(size_t)t * 128 + d] = __float2bfloat16(accv * sinv[h]);
}

// ---------------- head: logits = r @ p2^T, softmax ----------------
__global__ __launch_bounds__(256) void head_k(const __hip_bfloat16* __restrict__ r,
                                              const float* __restrict__ p2w,
                                              const float* __restrict__ p2b,
                                              float* __restrict__ out) {
    int t = blockIdx.x * 4 + (threadIdx.x >> 6);
    int lane = threadIdx.x & 63;
    float r0 = __bfloat162float(r[(size_t)t * 128 + lane]);
    float r1 = __bfloat162float(r[(size_t)t * 128 + 64 + lane]);
    float lg[5];
#pragma unroll
    for (int kk = 0; kk < 5; ++kk) {
        float p = r0 * p2w[kk * 128 + lane] + r1 * p2w[kk * 128 + 64 + lane];
#pragma unroll
        for (int off = 32; off; off >>= 1) p += __shfl_xor(p, off, 64);
        lg[kk] = p + p2b[kk];
    }
    if (lane == 0) {
        float mx = lg[0];
#pragma unroll
        for (int kk = 1; kk < 5; ++kk) mx = fmaxf(mx, lg[kk]);
        float e[5], s = 0.f;
#pragma unroll
        for (int kk = 0; kk < 5; ++kk) { e[kk] = expf(lg[kk] - mx); s += e[kk]; }
        float si = 1.f / s;
#pragma unroll
        for (int kk = 0; kk < 5; ++kk) out[(size_t)t * 5 + kk] = e[kk] * si;
    }
}

// ---------------- host launch ----------------

extern "C" void kernel_launch(void* const* d_in, const int* in_sizes, int n_in,
                              void* d_out, int out_size, void* d_ws, size_t ws_size,
                              hipStream_t stream) {
    const int* src = (const int*)d_in[0];
    const int* dst = (const int*)d_in[1];
    const int* neg = (const int*)d_in[2];
    const int* eidx = (const int*)d_in[3];
    const float* ts = (const float*)d_in[4];
    const float* node_feats = (const float*)d_in[5];
    const float* edge_feats = (const float*)d_in[6];
    const float* node_lin_w = (const float*)d_in[7];
    const float* node_lin_b = (const float*)d_in[8];
    const float* edge_lin_w = (const float*)d_in[9];
    const float* edge_lin_b = (const float*)d_in[10];
    const float* time_w = (const float*)d_in[11];
    const float* time_b = (const float*)d_in[12];
    const float* tok_w = (const float*)d_in[13];
    const float* tok_b = (const float*)d_in[14];
    const float* qkv_w = (const float*)d_in[15];
    const float* qkv_b = (const float*)d_in[16];
    const float* attn_w = (const float*)d_in[17];
    const float* attn_b = (const float*)d_in[18];
    const float* ln1_s = (const float*)d_in[19];
    const float* ln1_b = (const float*)d_in[20];
    const float* ln2_s = (const float*)d_in[21];
    const float* ln2_b = (const float*)d_in[22];
    const float* ff1_w = (const float*)d_in[23];
    const float* ff1_b = (const float*)d_in[24];
    const float* ff2_w = (const float*)d_in[25];
    const float* ff2_b = (const float*)d_in[26];
    const float* p1_w = (const float*)d_in[27];
    const float* p1_b = (const float*)d_in[28];
    const float* p2_w = (const float*)d_in[29];
    const float* p2_b = (const float*)d_in[30];
    float* out = (float*)d_out;

    char* w = (char*)d_ws;
    auto alloc = [&](size_t bytes) {
        char* p = w;
        w += (bytes + 255) & ~(size_t)255;
        return p;
    };
    // persistent regions
    float* x = (float*)alloc((size_t)NTOK * 128 * 4);          // 50.3 MB
    __hip_bfloat16* h = (__hip_bfloat16*)alloc((size_t)NTOK * 128 * 2);  // 25.2 MB (also xb)
    char* big = alloc((size_t)NTOK * 512 * 2);                 // 100.7 MB: qkv+o / u
    __hip_bfloat16* qkvb = (__hip_bfloat16*)big;
    __hip_bfloat16* ob = (__hip_bfloat16*)(big + (size_t)NTOK * 384 * 2);
    __hip_bfloat16* ub = (__hip_bfloat16*)big;
    char* scratch = alloc((size_t)(20000 * 256 * 4 + NB * 128 * 4));  // 37.3 MB: P12+E / r
    float* P12 = (float*)scratch;
    float* E = (float*)(scratch + (size_t)20000 * 256 * 4);
    __hip_bfloat16* rb = (__hip_bfloat16*)scratch;
    __hip_bfloat16* Aemb = (__hip_bfloat16*)alloc((size_t)NB * 192 * 2);
    __hip_bfloat16* nfb = (__hip_bfloat16*)alloc((size_t)NNODES * 128 * 2);
    // small weights
    __hip_bfloat16* A12 = (__hip_bfloat16*)alloc(256 * 128 * 2);
    __hip_bfloat16* AE = (__hip_bfloat16*)alloc(128 * 192 * 2);
    float* bfold = (float*)alloc(128 * 4);
    __hip_bfloat16* qkvwb = (__hip_bfloat16*)alloc(2 * 384 * 128 * 2);
    __hip_bfloat16* attnwb = (__hip_bfloat16*)alloc(2 * 128 * 128 * 2);
    __hip_bfloat16* ff1wb = (__hip_bfloat16*)alloc(2 * 512 * 128 * 2);
    __hip_bfloat16* ff2wb = (__hip_bfloat16*)alloc(2 * 128 * 512 * 2);
    __hip_bfloat16* p1wb = (__hip_bfloat16*)alloc(128 * 128 * 2);
    int* cnt = (int*)alloc(NNODES * 4);
    int* starts = (int*)alloc(NNODES * 4);
    int* cursor = (int*)alloc(NNODES * 4);
    int* order = (int*)alloc(NTOK * 4);
    int* node_of = (int*)alloc(NTOK * 4);

    hipMemsetAsync(cnt, 0, NNODES * 4, stream);
    hipMemsetAsync(cursor, 0, NNODES * 4, stream);

    // weight conversions
    auto cvt = [&](const float* in, __hip_bfloat16* outp, int n) {
        int blocks = (n + 255) / 256;
        if (blocks > 2048) blocks = 2048;
        convert_k<<<blocks, 256, 0, stream>>>(in, outp, n);
    };
    cvt(node_feats, nfb, NNODES * 128);
    cvt(qkv_w, qkvwb, 2 * 384 * 128);
    cvt(attn_w, attnwb, 2 * 128 * 128);
    cvt(ff1_w, ff1wb, 2 * 512 * 128);
    cvt(ff2_w, ff2wb, 2 * 128 * 512);
    cvt(p1_w, p1wb, 128 * 128);

    fold12_k<<<128, 256, 0, stream>>>(tok_w, node_lin_w, A12);
    foldE_k<<<96, 256, 0, stream>>>(tok_w, edge_lin_w, AE);
    foldb_k<<<1, 128, 0, stream>>>(tok_w, tok_b, node_lin_b, edge_lin_b, bfold);

    count_k<<<(NTOK + 255) / 256, 256, 0, stream>>>(src, dst, neg, cnt);
    scan_k<<<1, 256, 0, stream>>>(cnt, starts, NNODES);
    scatter_k<<<(NTOK + 255) / 256, 256, 0, stream>>>(src, dst, neg, starts, cursor, order, node_of);

    aemb_k<<<(NB * 192 + 255) / 256, 256, 0, stream>>>(eidx, ts, edge_feats, time_w, time_b, Aemb);

    // P12 = nfb @ A12^T  (M=20000, N=256, K=128)
    gemm_k<MODE_F32><<<dim3(157, 2), 256, 0, stream>>>(nfb, A12, nullptr, P12, nullptr,
                                                       NNODES, 256, 128);
    // E = Aemb @ AE^T + bfold  (M=32768, N=128, K=192)
    gemm_k<MODE_F32><<<dim3(256, 1), 256, 0, stream>>>(Aemb, AE, bfold, E, nullptr,
                                                       NB, 128, 192);
    // x = relu(gathered sum)
    asm_k<<<NTOK / 2, 256, 0, stream>>>(src, dst, neg, P12, E, x);

    const int gm = NTOK / 128;  // 768
    for (int l = 0; l < 2; ++l) {
        ln_k<<<NTOK / 4, 256, 0, stream>>>(x, ln1_s + l * 128, ln1_b + l * 128, h);
        gemm_k<MODE_BF16><<<dim3(gm, 3), 256, 0, stream>>>(
            h, qkvwb + (size_t)l * 384 * 128, qkv_b + l * 384, nullptr, qkvb,
            NTOK, 384, 128);
        attn_k<<<NTOK, 128, 0, stream>>>(qkvb, node_of, starts, cnt, order, ob);
        gemm_k<MODE_ADD><<<dim3(gm, 1), 256, 0, stream>>>(
            ob, attnwb + (size_t)l * 128 * 128, attn_b + l * 128, x, nullptr,
            NTOK, 128, 128);
        ln_k<<<NTOK / 4, 256, 0, stream>>>(x, ln2_s + l * 128, ln2_b + l * 128, h);
        gemm_k<MODE_GELU_BF16><<<dim3(gm, 4), 256, 0, stream>>>(
            h, ff1wb + (size_t)l * 512 * 128, ff1_b + l * 512, nullptr, ub,
            NTOK, 512, 128);
        if (l == 0)
            gemm_k<MODE_ADD><<<dim3(gm, 1), 256, 0, stream>>>(
                ub, ff2wb + (size_t)l * 128 * 512, ff2_b + l * 128, x, nullptr,
                NTOK, 128, 512);
        else
            gemm_k<MODE_ADD_BF16><<<dim3(gm, 1), 256, 0, stream>>>(
                ub, ff2wb + (size_t)l * 128 * 512, ff2_b + l * 128, x, h,
                NTOK, 128, 512);
    }

    // r = relu(xb @ p1^T + b)
    gemm_k<MODE_RELU_BF16><<<dim3(gm, 1), 256, 0, stream>>>(h, p1wb, p1_b, nullptr, rb,
                                                            NTOK, 128, 128);
    head_k<<<NTOK / 4, 256, 0, stream>>>(rb, p2_w, p2_b, out);
}

// Round 3
// 1063.371 us; speedup vs baseline: 3.1858x; 1.0566x over previous
//
#include <hip/hip_runtime.h>
#include <hip/hip_bf16.h>
#include <math.h>

#define NB 32768
#define NTOK (3 * NB)
#define NNODES 20000
#define MAXL 64

typedef short bf16x8 __attribute__((ext_vector_type(8)));
typedef float f32x4 __attribute__((ext_vector_type(4)));

// ---------------- small setup kernels ----------------

__global__ void convert_k(const float* __restrict__ in, __hip_bfloat16* __restrict__ out, int n) {
    int i = blockIdx.x * 256 + threadIdx.x;
    int stride = gridDim.x * 256;
    for (; i < n; i += stride) out[i] = __float2bfloat16(in[i]);
}

__global__ void fold12_k(const float* __restrict__ tok_w, const float* __restrict__ nl_w,
                         __hip_bfloat16* __restrict__ A12) {
    int idx = blockIdx.x * 256 + threadIdx.x;
    if (idx >= 256 * 128) return;
    int n = idx >> 7, f = idx & 127;
    const float* tw = (n < 128) ? (tok_w + n * 512) : (tok_w + (n - 128) * 512 + 128);
    float acc = 0.f;
    for (int c = 0; c < 128; ++c) acc += tw[c] * nl_w[c * 128 + f];
    A12[idx] = __float2bfloat16(acc);
}

__global__ void foldE_k(const float* __restrict__ tok_w, const float* __restrict__ el_w,
                        __hip_bfloat16* __restrict__ AE) {
    int idx = blockIdx.x * 256 + threadIdx.x;
    if (idx >= 128 * 192) return;
    int d = idx / 192, j = idx % 192;
    float acc;
    if (j < 64) {
        acc = 0.f;
        for (int c = 0; c < 128; ++c) acc += tok_w[d * 512 + 256 + c] * el_w[c * 64 + j];
    } else {
        acc = tok_w[d * 512 + 384 + (j - 64)];
    }
    AE[idx] = __float2bfloat16(acc);
}

__global__ void foldb_k(const float* __restrict__ tok_w, const float* __restrict__ tok_b,
                        const float* __restrict__ nl_b, const float* __restrict__ el_b,
                        float* __restrict__ bf) {
    int d = threadIdx.x;
    if (d >= 128) return;
    float acc = tok_b[d];
    for (int c = 0; c < 128; ++c)
        acc += (tok_w[d * 512 + c] + tok_w[d * 512 + 128 + c]) * nl_b[c];
    for (int c = 0; c < 128; ++c)
        acc += tok_w[d * 512 + 256 + c] * el_b[c];
    bf[d] = acc;
}

__device__ __forceinline__ int self_node(int t, const int* src, const int* dst, const int* neg) {
    if (t < NB) return src[t];
    if (t < 2 * NB) return dst[t - NB];
    return neg[t - 2 * NB];
}

__global__ void count_k(const int* __restrict__ src, const int* __restrict__ dst,
                        const int* __restrict__ neg, int* __restrict__ cnt) {
    int t = blockIdx.x * 256 + threadIdx.x;
    if (t >= NTOK) return;
    atomicAdd(&cnt[self_node(t, src, dst, neg)], 1);
}

__global__ void scan_k(const int* __restrict__ cnt, int* __restrict__ starts, int n) {
    __shared__ int buf[256];
    __shared__ int carry;
    int d = threadIdx.x;
    if (d == 0) carry = 0;
    __syncthreads();
    for (int base = 0; base < n; base += 256) {
        int i = base + d;
        int v = (i < n) ? cnt[i] : 0;
        buf[d] = v;
        __syncthreads();
        for (int off = 1; off < 256; off <<= 1) {
            int t = (d >= off) ? buf[d - off] : 0;
            __syncthreads();
            buf[d] += t;
            __syncthreads();
        }
        if (i < n) starts[i] = carry + buf[d] - v;
        __syncthreads();
        if (d == 255) carry += buf[255];
        __syncthreads();
    }
}

__global__ void scatter_k(const int* __restrict__ src, const int* __restrict__ dst,
                          const int* __restrict__ neg, const int* __restrict__ starts,
                          int* __restrict__ cursor, int* __restrict__ order) {
    int t = blockIdx.x * 256 + threadIdx.x;
    if (t >= NTOK) return;
    int node = self_node(t, src, dst, neg);
    int p = atomicAdd(&cursor[node], 1);
    order[starts[node] + p] = t;
}

__global__ void aemb_k(const int* __restrict__ eidx, const float* __restrict__ ts,
                       const float* __restrict__ ef, const float* __restrict__ tw,
                       const float* __restrict__ tb, __hip_bfloat16* __restrict__ Aemb) {
    int idx = blockIdx.x * 256 + threadIdx.x;
    if (idx >= NB * 192) return;
    int m = idx / 192, j = idx % 192;
    float v;
    if (j < 64) v = ef[(size_t)eidx[m] * 64 + j];
    else { int c = j - 64; v = cosf(ts[m] * tw[c] + tb[c]); }
    Aemb[idx] = __float2bfloat16(v);
}

// x[p] = relu(gathered sum) in SORTED order; h[p] = LN1_l0(x[p])
__global__ __launch_bounds__(256) void asm_emb_k(
    const int* __restrict__ order, const int* __restrict__ src, const int* __restrict__ dst,
    const int* __restrict__ neg, const float* __restrict__ P12, const float* __restrict__ E,
    const float* __restrict__ s, const float* __restrict__ b,
    float* __restrict__ x, __hip_bfloat16* __restrict__ h) {
    int p = blockIdx.x * 4 + (threadIdx.x >> 6);
    int lane = threadIdx.x & 63;
    int t = order[p];
    int m, self, other;
    if (t < NB) { m = t; self = src[m]; other = dst[m]; }
    else if (t < 2 * NB) { m = t - NB; self = dst[m]; other = src[m]; }
    else { m = t - 2 * NB; self = neg[m]; other = src[m]; }
    int d0 = lane, d1 = lane + 64;
    float v0 = P12[(size_t)self * 256 + d0] + P12[(size_t)other * 256 + 128 + d0] +
               E[(size_t)m * 128 + d0];
    float v1 = P12[(size_t)self * 256 + d1] + P12[(size_t)other * 256 + 128 + d1] +
               E[(size_t)m * 128 + d1];
    v0 = fmaxf(v0, 0.f);
    v1 = fmaxf(v1, 0.f);
    float sum = v0 + v1;
#pragma unroll
    for (int off = 32; off; off >>= 1) sum += __shfl_xor(sum, off, 64);
    float mean = sum * (1.f / 128.f);
    float c0 = v0 - mean, c1 = v1 - mean;
    float vs = c0 * c0 + c1 * c1;
#pragma unroll
    for (int off = 32; off; off >>= 1) vs += __shfl_xor(vs, off, 64);
    float inv = rsqrtf(vs * (1.f / 128.f) + 1e-5f);
    x[(size_t)p * 128 + d0] = v0;
    x[(size_t)p * 128 + d1] = v1;
    h[(size_t)p * 128 + d0] = __float2bfloat16(c0 * inv * s[d0] + b[d0]);
    h[(size_t)p * 128 + d1] = __float2bfloat16(c1 * inv * s[d1] + b[d1]);
}

// ---------------- plain MFMA GEMM (C = A@B^T + bias) ----------------
#define MODE_F32 0
#define MODE_BF16 1

template <int MODE>
__global__ __launch_bounds__(256) void gemm_k(
    const __hip_bfloat16* __restrict__ A, const __hip_bfloat16* __restrict__ B,
    const float* __restrict__ bias, float* __restrict__ Cf,
    __hip_bfloat16* __restrict__ Cb, int M, int N, int K) {
    __shared__ float4 As4[1024];
    __shared__ float4 Bs4[1024];
    int tid = threadIdx.x;
    int lane = tid & 63, wid = tid >> 6;
    int wm = wid & 1, wn = wid >> 1;
    int mBase = blockIdx.x * 128, nBase = blockIdx.y * 128;
    const float4 fzero = {0.f, 0.f, 0.f, 0.f};
    f32x4 acc[4][4];
#pragma unroll
    for (int i = 0; i < 4; ++i)
#pragma unroll
        for (int j = 0; j < 4; ++j) {
            f32x4 z = {0.f, 0.f, 0.f, 0.f};
            acc[i][j] = z;
        }
    bf16x8* AsV = reinterpret_cast<bf16x8*>(As4);
    bf16x8* BsV = reinterpret_cast<bf16x8*>(Bs4);

    for (int k0 = 0; k0 < K; k0 += 64) {
#pragma unroll
        for (int i = 0; i < 4; ++i) {
            int cid = i * 256 + tid;
            int r = cid >> 3, c = cid & 7;
            int sidx = r * 8 + (c ^ (r & 7));
            int gr = mBase + r;
            float4 va = fzero;
            if (gr < M)
                va = *reinterpret_cast<const float4*>(A + (size_t)gr * K + k0 + c * 8);
            As4[sidx] = va;
            int gn = nBase + r;
            Bs4[sidx] = *reinterpret_cast<const float4*>(B + (size_t)gn * K + k0 + c * 8);
        }
        __syncthreads();
#pragma unroll
        for (int kk = 0; kk < 2; ++kk) {
            bf16x8 a[4], b[4];
            int ccol = kk * 4 + (lane >> 4);
#pragma unroll
            for (int f = 0; f < 4; ++f) {
                int ra = wm * 64 + f * 16 + (lane & 15);
                a[f] = AsV[ra * 8 + (ccol ^ (ra & 7))];
                int rb = wn * 64 + f * 16 + (lane & 15);
                b[f] = BsV[rb * 8 + (ccol ^ (rb & 7))];
            }
#pragma unroll
            for (int fm = 0; fm < 4; ++fm)
#pragma unroll
                for (int fn = 0; fn < 4; ++fn)
                    acc[fm][fn] = __builtin_amdgcn_mfma_f32_16x16x32_bf16(
                        a[fm], b[fn], acc[fm][fn], 0, 0, 0);
        }
        __syncthreads();
    }

    int colBase = nBase + wn * 64;
#pragma unroll
    for (int fm = 0; fm < 4; ++fm) {
        int row0 = mBase + wm * 64 + fm * 16 + (lane >> 4) * 4;
#pragma unroll
        for (int fn = 0; fn < 4; ++fn) {
            int col = colBase + fn * 16 + (lane & 15);
            float bv = bias ? bias[col] : 0.f;
#pragma unroll
            for (int j = 0; j < 4; ++j) {
                int row = row0 + j;
                if (row >= M) continue;
                float v = acc[fm][fn][j] + bv;
                size_t off = (size_t)row * N + col;
                if (MODE == MODE_F32) Cf[off] = v;
                else Cb[off] = __float2bfloat16(v);
            }
        }
    }
}

// ---------------- GEMM(N=128) + residual + LN epilogue ----------------
// x += A@B^T + bias ; h = LN(x; s,b)
__global__ __launch_bounds__(256) void gemm_ln_k(
    const __hip_bfloat16* __restrict__ A, const __hip_bfloat16* __restrict__ B,
    const float* __restrict__ bias, float* __restrict__ x,
    const float* __restrict__ s, const float* __restrict__ b,
    __hip_bfloat16* __restrict__ h) {
    __shared__ __align__(16) char smem[65536];
    float4* As4 = (float4*)smem;
    float4* Bs4 = (float4*)(smem + 16384);
    float* rowbuf = (float*)smem;
    int tid = threadIdx.x;
    int lane = tid & 63, wid = tid >> 6;
    int wm = wid & 1, wn = wid >> 1;
    int mBase = blockIdx.x * 128;
    f32x4 acc[4][4];
#pragma unroll
    for (int i = 0; i < 4; ++i)
#pragma unroll
        for (int j = 0; j < 4; ++j) {
            f32x4 z = {0.f, 0.f, 0.f, 0.f};
            acc[i][j] = z;
        }
    bf16x8* AsV = reinterpret_cast<bf16x8*>(As4);
    bf16x8* BsV = reinterpret_cast<bf16x8*>(Bs4);
    for (int k0 = 0; k0 < 128; k0 += 64) {
#pragma unroll
        for (int i = 0; i < 4; ++i) {
            int cid = i * 256 + tid;
            int r = cid >> 3, c = cid & 7;
            int sidx = r * 8 + (c ^ (r & 7));
            As4[sidx] = *reinterpret_cast<const float4*>(A + (size_t)(mBase + r) * 128 + k0 + c * 8);
            Bs4[sidx] = *reinterpret_cast<const float4*>(B + (size_t)r * 128 + k0 + c * 8);
        }
        __syncthreads();
#pragma unroll
        for (int kk = 0; kk < 2; ++kk) {
            bf16x8 a[4], bb[4];
            int ccol = kk * 4 + (lane >> 4);
#pragma unroll
            for (int f = 0; f < 4; ++f) {
                int ra = wm * 64 + f * 16 + (lane & 15);
                a[f] = AsV[ra * 8 + (ccol ^ (ra & 7))];
                int rb = wn * 64 + f * 16 + (lane & 15);
                bb[f] = BsV[rb * 8 + (ccol ^ (rb & 7))];
            }
#pragma unroll
            for (int fm = 0; fm < 4; ++fm)
#pragma unroll
                for (int fn = 0; fn < 4; ++fn)
                    acc[fm][fn] = __builtin_amdgcn_mfma_f32_16x16x32_bf16(
                        a[fm], bb[fn], acc[fm][fn], 0, 0, 0);
        }
        __syncthreads();
    }
    // epilogue: residual add, write x, stash to rowbuf
#pragma unroll
    for (int fm = 0; fm < 4; ++fm) {
        int rl0 = wm * 64 + fm * 16 + (lane >> 4) * 4;
#pragma unroll
        for (int fn = 0; fn < 4; ++fn) {
            int col = wn * 64 + fn * 16 + (lane & 15);
            float bv = bias[col];
#pragma unroll
            for (int j = 0; j < 4; ++j) {
                int rl = rl0 + j;
                size_t off = (size_t)(mBase + rl) * 128 + col;
                float v = acc[fm][fn][j] + bv + x[off];
                x[off] = v;
                rowbuf[rl * 128 + (col ^ ((rl & 7) << 2))] = v;
            }
        }
    }
    __syncthreads();
    // LN per row (thread pair per row)
    int row = tid >> 1, half = tid & 1;
    int swz = (row & 7) << 2;
    float sum = 0.f;
    for (int i = 0; i < 64; ++i) {
        int col = half * 64 + i;
        sum += rowbuf[row * 128 + (col ^ swz)];
    }
    sum += __shfl_xor(sum, 1, 64);
    float mean = sum * (1.f / 128.f);
    float vs = 0.f;
    for (int i = 0; i < 64; ++i) {
        int col = half * 64 + i;
        float c = rowbuf[row * 128 + (col ^ swz)] - mean;
        vs += c * c;
    }
    vs += __shfl_xor(vs, 1, 64);
    float inv = rsqrtf(vs * (1.f / 128.f) + 1e-5f);
    for (int i = 0; i < 64; ++i) {
        int col = half * 64 + i;
        float c = rowbuf[row * 128 + (col ^ swz)] - mean;
        h[(size_t)(mBase + row) * 128 + col] = __float2bfloat16(c * inv * s[col] + b[col]);
    }
}

// ---------------- fused FFN: x += gelu(h@W1^T+b1)@W2^T + b2 ; h' = LN or bf16(x) ----------------
template <bool DO_LN>
__global__ __launch_bounds__(256) void ff_fused_k(
    const __hip_bfloat16* __restrict__ hin, const __hip_bfloat16* __restrict__ W1,
    const float* __restrict__ b1, const __hip_bfloat16* __restrict__ W2,
    const float* __restrict__ b2, float* __restrict__ x,
    const float* __restrict__ s, const float* __restrict__ b,
    __hip_bfloat16* __restrict__ hout) {
    __shared__ __align__(16) char smem[81920];
    float4* hS4 = (float4*)smem;                    // 128x128 bf16 (2048 vec)
    float4* w1S4 = (float4*)(smem + 32768);         // 64x128 bf16 (1024 vec)
    unsigned short* uU16 = (unsigned short*)(smem + 49152);  // 128x64 bf16
    float4* uS4 = (float4*)(smem + 49152);
    float4* w2S4 = (float4*)(smem + 65536);         // 128x64 bf16 (1024 vec)
    float* rowbuf = (float*)smem;
    bf16x8* hV = (bf16x8*)hS4;
    bf16x8* w1V = (bf16x8*)w1S4;
    bf16x8* uV = (bf16x8*)uS4;
    bf16x8* w2V = (bf16x8*)w2S4;

    int tid = threadIdx.x;
    int lane = tid & 63, wid = tid >> 6;
    int wm = wid & 1, wn = wid >> 1;
    int mBase = blockIdx.x * 128;

    // stage h tile: 2048 16B vecs
#pragma unroll
    for (int i = 0; i < 8; ++i) {
        int cid = i * 256 + tid;
        int r = cid >> 4, c = cid & 15;
        hS4[r * 16 + (c ^ (r & 7))] =
            *reinterpret_cast<const float4*>(hin + (size_t)(mBase + r) * 128 + c * 8);
    }
    f32x4 acc2[4][4];
#pragma unroll
    for (int i = 0; i < 4; ++i)
#pragma unroll
        for (int j = 0; j < 4; ++j) {
            f32x4 z = {0.f, 0.f, 0.f, 0.f};
            acc2[i][j] = z;
        }
    __syncthreads();

    for (int ch = 0; ch < 8; ++ch) {
        // stage W1 chunk (64 ff rows x 128) and W2 chunk (128 out rows x 64)
#pragma unroll
        for (int i = 0; i < 4; ++i) {
            int cid = i * 256 + tid;
            int r = cid >> 4, c = cid & 15;
            w1S4[r * 16 + (c ^ (r & 7))] =
                *reinterpret_cast<const float4*>(W1 + (size_t)(ch * 64 + r) * 128 + c * 8);
            int r2 = cid >> 3, c2 = cid & 7;
            w2S4[r2 * 8 + (c2 ^ (r2 & 7))] =
                *reinterpret_cast<const float4*>(W2 + (size_t)r2 * 512 + ch * 64 + c2 * 8);
        }
        __syncthreads();
        // gemm1: S1[128 rows][64 ff] = h @ W1c^T
        f32x4 acc1[4][2];
#pragma unroll
        for (int i = 0; i < 4; ++i)
#pragma unroll
            for (int j = 0; j < 2; ++j) {
                f32x4 z = {0.f, 0.f, 0.f, 0.f};
                acc1[i][j] = z;
            }
#pragma unroll
        for (int kk = 0; kk < 4; ++kk) {
            int kvec = kk * 4 + (lane >> 4);
            bf16x8 a[4], bb[2];
#pragma unroll
            for (int f = 0; f < 4; ++f) {
                int ra = wm * 64 + f * 16 + (lane & 15);
                a[f] = hV[ra * 16 + (kvec ^ (ra & 7))];
            }
#pragma unroll
            for (int f = 0; f < 2; ++f) {
                int rb = wn * 32 + f * 16 + (lane & 15);
                bb[f] = w1V[rb * 16 + (kvec ^ (rb & 7))];
            }
#pragma unroll
            for (int fm = 0; fm < 4; ++fm)
#pragma unroll
                for (int fn = 0; fn < 2; ++fn)
                    acc1[fm][fn] = __builtin_amdgcn_mfma_f32_16x16x32_bf16(
                        a[fm], bb[fn], acc1[fm][fn], 0, 0, 0);
        }
        // gelu + write u to LDS
#pragma unroll
        for (int fm = 0; fm < 4; ++fm) {
            int rl0 = wm * 64 + fm * 16 + (lane >> 4) * 4;
#pragma unroll
            for (int fn = 0; fn < 2; ++fn) {
                int colL = wn * 32 + fn * 16 + (lane & 15);
                float bv = b1[ch * 64 + colL];
#pragma unroll
                for (int j = 0; j < 4; ++j) {
                    int rl = rl0 + j;
                    float v = acc1[fm][fn][j] + bv;
                    float g = 0.5f * v * (1.f + erff(v * 0.70710678118654752f));
                    __hip_bfloat16 gb = __float2bfloat16(g);
                    uU16[(rl * 8 + ((colL >> 3) ^ (rl & 7))) * 8 + (colL & 7)] =
                        *reinterpret_cast<unsigned short*>(&gb);
                }
            }
        }
        __syncthreads();
        // gemm2: acc2 += u @ W2c^T  (K=64)
#pragma unroll
        for (int kk = 0; kk < 2; ++kk) {
            int kvec = kk * 4 + (lane >> 4);
            bf16x8 a[4], bb[4];
#pragma unroll
            for (int f = 0; f < 4; ++f) {
                int ra = wm * 64 + f * 16 + (lane & 15);
                a[f] = uV[ra * 8 + (kvec ^ (ra & 7))];
                int rb = wn * 64 + f * 16 + (lane & 15);
                bb[f] = w2V[rb * 8 + (kvec ^ (rb & 7))];
            }
#pragma unroll
            for (int fm = 0; fm < 4; ++fm)
#pragma unroll
                for (int fn = 0; fn < 4; ++fn)
                    acc2[fm][fn] = __builtin_amdgcn_mfma_f32_16x16x32_bf16(
                        a[fm], bb[fn], acc2[fm][fn], 0, 0, 0);
        }
        __syncthreads();
    }

    // epilogue
#pragma unroll
    for (int fm = 0; fm < 4; ++fm) {
        int rl0 = wm * 64 + fm * 16 + (lane >> 4) * 4;
#pragma unroll
        for (int fn = 0; fn < 4; ++fn) {
            int col = wn * 64 + fn * 16 + (lane & 15);
            float bv = b2[col];
#pragma unroll
            for (int j = 0; j < 4; ++j) {
                int rl = rl0 + j;
                size_t off = (size_t)(mBase + rl) * 128 + col;
                float v = acc2[fm][fn][j] + bv + x[off];
                x[off] = v;
                if (DO_LN)
                    rowbuf[rl * 128 + (col ^ ((rl & 7) << 2))] = v;
                else
                    hout[off] = __float2bfloat16(v);
            }
        }
    }
    if (DO_LN) {
        __syncthreads();
        int row = tid >> 1, half = tid & 1;
        int swz = (row & 7) << 2;
        float sum = 0.f;
        for (int i = 0; i < 64; ++i) {
            int col = half * 64 + i;
            sum += rowbuf[row * 128 + (col ^ swz)];
        }
        sum += __shfl_xor(sum, 1, 64);
        float mean = sum * (1.f / 128.f);
        float vs = 0.f;
        for (int i = 0; i < 64; ++i) {
            int col = half * 64 + i;
            float c = rowbuf[row * 128 + (col ^ swz)] - mean;
            vs += c * c;
        }
        vs += __shfl_xor(vs, 1, 64);
        float inv = rsqrtf(vs * (1.f / 128.f) + 1e-5f);
        for (int i = 0; i < 64; ++i) {
            int col = half * 64 + i;
            float c = rowbuf[row * 128 + (col ^ swz)] - mean;
            hout[(size_t)(mBase + row) * 128 + col] =
                __float2bfloat16(c * inv * s[col] + b[col]);
        }
    }
}

// ---------------- attention: wave per group, groups contiguous ----------------
__global__ __launch_bounds__(256) void attn_k(
    const __hip_bfloat16* __restrict__ qkv, const int* __restrict__ starts,
    const int* __restrict__ cnt, __hip_bfloat16* __restrict__ o) {
    __shared__ float sc[4][4][MAXL];
    __shared__ float sinv[4][4];
    int wid = threadIdx.x >> 6, lane = threadIdx.x & 63;
    int node = blockIdx.x * 4 + wid;
    if (node >= NNODES) return;
    int st = starts[node];
    int len = cnt[node];
    if (len <= 0) return;
    if (len > MAXL) len = MAXL;
    const float scale = 0.17677669529663687f;
    int h01 = lane >> 5;         // head for dims 0..63
    for (int qi = 0; qi < len; ++qi) {
        const __hip_bfloat16* qrow = qkv + (size_t)(st + qi) * 384;
        float q0 = __bfloat162float(qrow[lane]);
        float q1 = __bfloat162float(qrow[64 + lane]);
        for (int j = 0; j < len; ++j) {
            const __hip_bfloat16* krow = qkv + (size_t)(st + j) * 384 + 128;
            float p0 = q0 * __bfloat162float(krow[lane]);
            float p1 = q1 * __bfloat162float(krow[64 + lane]);
#pragma unroll
            for (int off = 16; off; off >>= 1) {
                p0 += __shfl_xor(p0, off, 64);
                p1 += __shfl_xor(p1, off, 64);
            }
            if ((lane & 31) == 0) {
                sc[wid][h01][j] = p0 * scale;
                sc[wid][2 + h01][j] = p1 * scale;
            }
        }
        // softmax: 4 heads handled by 4 groups of 16 lanes
        int hh = lane >> 4, li = lane & 15;
        float mx = -1e30f;
        for (int j = li; j < len; j += 16) mx = fmaxf(mx, sc[wid][hh][j]);
#pragma unroll
        for (int off = 8; off; off >>= 1) mx = fmaxf(mx, __shfl_xor(mx, off, 64));
        float ssum = 0.f;
        for (int j = li; j < len; j += 16) {
            float e = __expf(sc[wid][hh][j] - mx);
            sc[wid][hh][j] = e;
            ssum += e;
        }
#pragma unroll
        for (int off = 8; off; off >>= 1) ssum += __shfl_xor(ssum, off, 64);
        if (li == 0) sinv[wid][hh] = 1.f / ssum;
        float a0 = 0.f, a1 = 0.f;
        for (int j = 0; j < len; ++j) {
            const __hip_bfloat16* vrow = qkv + (size_t)(st + j) * 384 + 256;
            a0 += sc[wid][h01][j] * __bfloat162float(vrow[lane]);
            a1 += sc[wid][2 + h01][j] * __bfloat162float(vrow[64 + lane]);
        }
        __hip_bfloat16* orow = o + (size_t)(st + qi) * 128;
        orow[lane] = __float2bfloat16(a0 * sinv[wid][h01]);
        orow[64 + lane] = __float2bfloat16(a1 * sinv[wid][2 + h01]);
    }
}

// ---------------- p1 GEMM + relu + head (logits+softmax) ----------------
__global__ __launch_bounds__(256) void p1head_k(
    const __hip_bfloat16* __restrict__ A, const __hip_bfloat16* __restrict__ B,
    const float* __restrict__ bias, const float* __restrict__ p2w,
    const float* __restrict__ p2b, const int* __restrict__ order,
    float* __restrict__ out) {
    __shared__ __align__(16) char smem[65536];
    __shared__ float p2s[640];
    __shared__ float p2bs[5];
    float4* As4 = (float4*)smem;
    float4* Bs4 = (float4*)(smem + 16384);
    float* rowbuf = (float*)smem;
    int tid = threadIdx.x;
    for (int i = tid; i < 640; i += 256) p2s[i] = p2w[i];
    if (tid < 5) p2bs[tid] = p2b[tid];
    int lane = tid & 63, wid = tid >> 6;
    int wm = wid & 1, wn = wid >> 1;
    int mBase = blockIdx.x * 128;
    f32x4 acc[4][4];
#pragma unroll
    for (int i = 0; i < 4; ++i)
#pragma unroll
        for (int j = 0; j < 4; ++j) {
            f32x4 z = {0.f, 0.f, 0.f, 0.f};
            acc[i][j] = z;
        }
    bf16x8* AsV = reinterpret_cast<bf16x8*>(As4);
    bf16x8* BsV = reinterpret_cast<bf16x8*>(Bs4);
    for (int k0 = 0; k0 < 128; k0 += 64) {
#pragma unroll
        for (int i = 0; i < 4; ++i) {
            int cid = i * 256 + tid;
            int r = cid >> 3, c = cid & 7;
            int sidx = r * 8 + (c ^ (r & 7));
            As4[sidx] = *reinterpret_cast<const float4*>(A + (size_t)(mBase + r) * 128 + k0 + c * 8);
            Bs4[sidx] = *reinterpret_cast<const float4*>(B + (size_t)r * 128 + k0 + c * 8);
        }
        __syncthreads();
#pragma unroll
        for (int kk = 0; kk < 2; ++kk) {
            bf16x8 a[4], bb[4];
            int ccol = kk * 4 + (lane >> 4);
#pragma unroll
            for (int f = 0; f < 4; ++f) {
                int ra = wm * 64 + f * 16 + (lane & 15);
                a[f] = AsV[ra * 8 + (ccol ^ (ra & 7))];
                int rb = wn * 64 + f * 16 + (lane & 15);
                bb[f] = BsV[rb * 8 + (ccol ^ (rb & 7))];
            }
#pragma unroll
            for (int fm = 0; fm < 4; ++fm)
#pragma unroll
                for (int fn = 0; fn < 4; ++fn)
                    acc[fm][fn] = __builtin_amdgcn_mfma_f32_16x16x32_bf16(
                        a[fm], bb[fn], acc[fm][fn], 0, 0, 0);
        }
        __syncthreads();
    }
#pragma unroll
    for (int fm = 0; fm < 4; ++fm) {
        int rl0 = wm * 64 + fm * 16 + (lane >> 4) * 4;
#pragma unroll
        for (int fn = 0; fn < 4; ++fn) {
            int col = wn * 64 + fn * 16 + (lane & 15);
            float bv = bias[col];
#pragma unroll
            for (int j = 0; j < 4; ++j) {
                int rl = rl0 + j;
                rowbuf[rl * 128 + (col ^ ((rl & 7) << 2))] = fmaxf(acc[fm][fn][j] + bv, 0.f);
            }
        }
    }
    __syncthreads();
    int row = tid >> 1, half = tid & 1;
    int swz = (row & 7) << 2;
    float lg[5] = {0.f, 0.f, 0.f, 0.f, 0.f};
    for (int i = 0; i < 64; ++i) {
        int col = half * 64 + i;
        float rv = rowbuf[row * 128 + (col ^ swz)];
#pragma unroll
        for (int k = 0; k < 5; ++k) lg[k] += rv * p2s[k * 128 + col];
    }
#pragma unroll
    for (int k = 0; k < 5; ++k) lg[k] += __shfl_xor(lg[k], 1, 64);
    if (half == 0) {
        float mx = -1e30f;
#pragma unroll
        for (int k = 0; k < 5; ++k) {
            lg[k] += p2bs[k];
            mx = fmaxf(mx, lg[k]);
        }
        float e[5], ssum = 0.f;
#pragma unroll
        for (int k = 0; k < 5; ++k) {
            e[k] = __expf(lg[k] - mx);
            ssum += e[k];
        }
        float si = 1.f / ssum;
        int t = order[mBase + row];
#pragma unroll
        for (int k = 0; k < 5; ++k) out[(size_t)t * 5 + k] = e[k] * si;
    }
}

// ---------------- host launch ----------------

extern "C" void kernel_launch(void* const* d_in, const int* in_sizes, int n_in,
                              void* d_out, int out_size, void* d_ws, size_t ws_size,
                              hipStream_t stream) {
    const int* src = (const int*)d_in[0];
    const int* dst = (const int*)d_in[1];
    const int* neg = (const int*)d_in[2];
    const int* eidx = (const int*)d_in[3];
    const float* ts = (const float*)d_in[4];
    const float* node_feats = (const float*)d_in[5];
    const float* edge_feats = (const float*)d_in[6];
    const float* node_lin_w = (const float*)d_in[7];
    const float* node_lin_b = (const float*)d_in[8];
    const float* edge_lin_w = (const float*)d_in[9];
    const float* edge_lin_b = (const float*)d_in[10];
    const float* time_w = (const float*)d_in[11];
    const float* time_b = (const float*)d_in[12];
    const float* tok_w = (const float*)d_in[13];
    const float* tok_b = (const float*)d_in[14];
    const float* qkv_w = (const float*)d_in[15];
    const float* qkv_b = (const float*)d_in[16];
    const float* attn_w = (const float*)d_in[17];
    const float* attn_b = (const float*)d_in[18];
    const float* ln1_s = (const float*)d_in[19];
    const float* ln1_b = (const float*)d_in[20];
    const float* ln2_s = (const float*)d_in[21];
    const float* ln2_b = (const float*)d_in[22];
    const float* ff1_w = (const float*)d_in[23];
    const float* ff1_b = (const float*)d_in[24];
    const float* ff2_w = (const float*)d_in[25];
    const float* ff2_b = (const float*)d_in[26];
    const float* p1_w = (const float*)d_in[27];
    const float* p1_b = (const float*)d_in[28];
    const float* p2_w = (const float*)d_in[29];
    const float* p2_b = (const float*)d_in[30];
    float* out = (float*)d_out;

    char* w = (char*)d_ws;
    auto alloc = [&](size_t bytes) {
        char* p = w;
        w += (bytes + 255) & ~(size_t)255;
        return p;
    };
    float* x = (float*)alloc((size_t)NTOK * 128 * 4);
    __hip_bfloat16* h = (__hip_bfloat16*)alloc((size_t)NTOK * 128 * 2);
    __hip_bfloat16* qkvb = (__hip_bfloat16*)alloc((size_t)NTOK * 384 * 2);
    __hip_bfloat16* ob = (__hip_bfloat16*)alloc((size_t)NTOK * 128 * 2);
    float* P12 = (float*)alloc((size_t)NNODES * 256 * 4);
    float* E = (float*)alloc((size_t)NB * 128 * 4);
    __hip_bfloat16* Aemb = (__hip_bfloat16*)alloc((size_t)NB * 192 * 2);
    __hip_bfloat16* nfb = (__hip_bfloat16*)alloc((size_t)NNODES * 128 * 2);
    __hip_bfloat16* A12 = (__hip_bfloat16*)alloc(256 * 128 * 2);
    __hip_bfloat16* AE = (__hip_bfloat16*)alloc(128 * 192 * 2);
    float* bfold = (float*)alloc(128 * 4);
    __hip_bfloat16* qkvwb = (__hip_bfloat16*)alloc(2 * 384 * 128 * 2);
    __hip_bfloat16* attnwb = (__hip_bfloat16*)alloc(2 * 128 * 128 * 2);
    __hip_bfloat16* ff1wb = (__hip_bfloat16*)alloc(2 * 512 * 128 * 2);
    __hip_bfloat16* ff2wb = (__hip_bfloat16*)alloc(2 * 128 * 512 * 2);
    __hip_bfloat16* p1wb = (__hip_bfloat16*)alloc(128 * 128 * 2);
    int* cnt = (int*)alloc(NNODES * 4);
    int* starts = (int*)alloc(NNODES * 4);
    int* cursor = (int*)alloc(NNODES * 4);
    int* order = (int*)alloc(NTOK * 4);

    hipMemsetAsync(cnt, 0, NNODES * 4, stream);
    hipMemsetAsync(cursor, 0, NNODES * 4, stream);

    auto cvt = [&](const float* in, __hip_bfloat16* outp, int n) {
        int blocks = (n + 255) / 256;
        if (blocks > 2048) blocks = 2048;
        convert_k<<<blocks, 256, 0, stream>>>(in, outp, n);
    };
    cvt(node_feats, nfb, NNODES * 128);
    cvt(qkv_w, qkvwb, 2 * 384 * 128);
    cvt(attn_w, attnwb, 2 * 128 * 128);
    cvt(ff1_w, ff1wb, 2 * 512 * 128);
    cvt(ff2_w, ff2wb, 2 * 128 * 512);
    cvt(p1_w, p1wb, 128 * 128);

    fold12_k<<<128, 256, 0, stream>>>(tok_w, node_lin_w, A12);
    foldE_k<<<96, 256, 0, stream>>>(tok_w, edge_lin_w, AE);
    foldb_k<<<1, 128, 0, stream>>>(tok_w, tok_b, node_lin_b, edge_lin_b, bfold);

    count_k<<<(NTOK + 255) / 256, 256, 0, stream>>>(src, dst, neg, cnt);
    scan_k<<<1, 256, 0, stream>>>(cnt, starts, NNODES);
    scatter_k<<<(NTOK + 255) / 256, 256, 0, stream>>>(src, dst, neg, starts, cursor, order);

    aemb_k<<<(NB * 192 + 255) / 256, 256, 0, stream>>>(eidx, ts, edge_feats, time_w, time_b, Aemb);

    gemm_k<MODE_F32><<<dim3(157, 2), 256, 0, stream>>>(nfb, A12, nullptr, P12, nullptr,
                                                       NNODES, 256, 128);
    gemm_k<MODE_F32><<<dim3(256, 1), 256, 0, stream>>>(Aemb, AE, bfold, E, nullptr,
                                                       NB, 128, 192);
    asm_emb_k<<<NTOK / 4, 256, 0, stream>>>(order, src, dst, neg, P12, E,
                                            ln1_s, ln1_b, x, h);

    const int gm = NTOK / 128;  // 768
    for (int l = 0; l < 2; ++l) {
        gemm_k<MODE_BF16><<<dim3(gm, 3), 256, 0, stream>>>(
            h, qkvwb + (size_t)l * 384 * 128, qkv_b + l * 384, nullptr, qkvb,
            NTOK, 384, 128);
        attn_k<<<(NNODES + 3) / 4, 256, 0, stream>>>(qkvb, starts, cnt, ob);
        gemm_ln_k<<<gm, 256, 0, stream>>>(ob, attnwb + (size_t)l * 128 * 128,
                                          attn_b + l * 128, x,
                                          ln2_s + l * 128, ln2_b + l * 128, h);
        if (l == 0)
            ff_fused_k<true><<<gm, 256, 0, stream>>>(
                h, ff1wb, ff1_b, ff2wb, ff2_b, x, ln1_s + 128, ln1_b + 128, h);
        else
            ff_fused_k<false><<<gm, 256, 0, stream>>>(
                h, ff1wb + (size_t)512 * 128, ff1_b + 512, ff2wb + (size_t)128 * 512,
                ff2_b + 128, x, nullptr, nullptr, h);
    }

    p1head_k<<<gm, 256, 0, stream>>>(h, p1wb, p1_b, p2_w, p2_b, order, out);
}

// Round 4
// 900.573 us; speedup vs baseline: 3.7618x; 1.1808x over previous
//
#include <hip/hip_runtime.h>
#include <hip/hip_bf16.h>
#include <math.h>

#define NB 32768
#define NTOK (3 * NB)
#define NNODES 20000
#define MAXL 64

typedef short bf16x8 __attribute__((ext_vector_type(8)));
typedef float f32x4 __attribute__((ext_vector_type(4)));

typedef __attribute__((address_space(3))) void lds_t;
typedef const __attribute__((address_space(1))) void gbl_t;

// ---------------- small setup kernels ----------------

__global__ void convert_k(const float* __restrict__ in, __hip_bfloat16* __restrict__ out, int n) {
    int i = blockIdx.x * 256 + threadIdx.x;
    int stride = gridDim.x * 256;
    for (; i < n; i += stride) out[i] = __float2bfloat16(in[i]);
}

__global__ void fold12_k(const float* __restrict__ tok_w, const float* __restrict__ nl_w,
                         __hip_bfloat16* __restrict__ A12) {
    int idx = blockIdx.x * 256 + threadIdx.x;
    if (idx >= 256 * 128) return;
    int n = idx >> 7, f = idx & 127;
    const float* tw = (n < 128) ? (tok_w + n * 512) : (tok_w + (n - 128) * 512 + 128);
    float acc = 0.f;
    for (int c = 0; c < 128; ++c) acc += tw[c] * nl_w[c * 128 + f];
    A12[idx] = __float2bfloat16(acc);
}

__global__ void foldE_k(const float* __restrict__ tok_w, const float* __restrict__ el_w,
                        __hip_bfloat16* __restrict__ AE) {
    int idx = blockIdx.x * 256 + threadIdx.x;
    if (idx >= 128 * 192) return;
    int d = idx / 192, j = idx % 192;
    float acc;
    if (j < 64) {
        acc = 0.f;
        for (int c = 0; c < 128; ++c) acc += tok_w[d * 512 + 256 + c] * el_w[c * 64 + j];
    } else {
        acc = tok_w[d * 512 + 384 + (j - 64)];
    }
    AE[idx] = __float2bfloat16(acc);
}

__global__ void foldb_k(const float* __restrict__ tok_w, const float* __restrict__ tok_b,
                        const float* __restrict__ nl_b, const float* __restrict__ el_b,
                        float* __restrict__ bf) {
    int d = threadIdx.x;
    if (d >= 128) return;
    float acc = tok_b[d];
    for (int c = 0; c < 128; ++c)
        acc += (tok_w[d * 512 + c] + tok_w[d * 512 + 128 + c]) * nl_b[c];
    for (int c = 0; c < 128; ++c)
        acc += tok_w[d * 512 + 256 + c] * el_b[c];
    bf[d] = acc;
}

__device__ __forceinline__ int self_node(int t, const int* src, const int* dst, const int* neg) {
    if (t < NB) return src[t];
    if (t < 2 * NB) return dst[t - NB];
    return neg[t - 2 * NB];
}

__global__ void count_k(const int* __restrict__ src, const int* __restrict__ dst,
                        const int* __restrict__ neg, int* __restrict__ cnt) {
    int t = blockIdx.x * 256 + threadIdx.x;
    if (t >= NTOK) return;
    atomicAdd(&cnt[self_node(t, src, dst, neg)], 1);
}

__global__ void scan_k(const int* __restrict__ cnt, int* __restrict__ starts, int n) {
    __shared__ int buf[256];
    __shared__ int carry;
    int d = threadIdx.x;
    if (d == 0) carry = 0;
    __syncthreads();
    for (int base = 0; base < n; base += 256) {
        int i = base + d;
        int v = (i < n) ? cnt[i] : 0;
        buf[d] = v;
        __syncthreads();
        for (int off = 1; off < 256; off <<= 1) {
            int t = (d >= off) ? buf[d - off] : 0;
            __syncthreads();
            buf[d] += t;
            __syncthreads();
        }
        if (i < n) starts[i] = carry + buf[d] - v;
        __syncthreads();
        if (d == 255) carry += buf[255];
        __syncthreads();
    }
}

__global__ void scatter_k(const int* __restrict__ src, const int* __restrict__ dst,
                          const int* __restrict__ neg, const int* __restrict__ starts,
                          int* __restrict__ cursor, int* __restrict__ order) {
    int t = blockIdx.x * 256 + threadIdx.x;
    if (t >= NTOK) return;
    int node = self_node(t, src, dst, neg);
    int p = atomicAdd(&cursor[node], 1);
    order[starts[node] + p] = t;
}

__global__ void aemb_k(const int* __restrict__ eidx, const float* __restrict__ ts,
                       const float* __restrict__ ef, const float* __restrict__ tw,
                       const float* __restrict__ tb, __hip_bfloat16* __restrict__ Aemb) {
    int idx = blockIdx.x * 256 + threadIdx.x;
    if (idx >= NB * 192) return;
    int m = idx / 192, j = idx % 192;
    float v;
    if (j < 64) v = ef[(size_t)eidx[m] * 64 + j];
    else { int c = j - 64; v = cosf(ts[m] * tw[c] + tb[c]); }
    Aemb[idx] = __float2bfloat16(v);
}

// x[p] = relu(gathered sum) in SORTED order; h[p] = LN1_l0(x[p])
__global__ __launch_bounds__(256) void asm_emb_k(
    const int* __restrict__ order, const int* __restrict__ src, const int* __restrict__ dst,
    const int* __restrict__ neg, const float* __restrict__ P12, const float* __restrict__ E,
    const float* __restrict__ s, const float* __restrict__ b,
    float* __restrict__ x, __hip_bfloat16* __restrict__ h) {
    int p = blockIdx.x * 4 + (threadIdx.x >> 6);
    int lane = threadIdx.x & 63;
    int t = order[p];
    int m, self, other;
    if (t < NB) { m = t; self = src[m]; other = dst[m]; }
    else if (t < 2 * NB) { m = t - NB; self = dst[m]; other = src[m]; }
    else { m = t - 2 * NB; self = neg[m]; other = src[m]; }
    int d0 = lane, d1 = lane + 64;
    float v0 = P12[(size_t)self * 256 + d0] + P12[(size_t)other * 256 + 128 + d0] +
               E[(size_t)m * 128 + d0];
    float v1 = P12[(size_t)self * 256 + d1] + P12[(size_t)other * 256 + 128 + d1] +
               E[(size_t)m * 128 + d1];
    v0 = fmaxf(v0, 0.f);
    v1 = fmaxf(v1, 0.f);
    float sum = v0 + v1;
#pragma unroll
    for (int off = 32; off; off >>= 1) sum += __shfl_xor(sum, off, 64);
    float mean = sum * (1.f / 128.f);
    float c0 = v0 - mean, c1 = v1 - mean;
    float vs = c0 * c0 + c1 * c1;
#pragma unroll
    for (int off = 32; off; off >>= 1) vs += __shfl_xor(vs, off, 64);
    float inv = rsqrtf(vs * (1.f / 128.f) + 1e-5f);
    x[(size_t)p * 128 + d0] = v0;
    x[(size_t)p * 128 + d1] = v1;
    h[(size_t)p * 128 + d0] = __float2bfloat16(c0 * inv * s[d0] + b[d0]);
    h[(size_t)p * 128 + d1] = __float2bfloat16(c1 * inv * s[d1] + b[d1]);
}

// ---------------- fast gelu (A&S 7.1.26 erf, |err|<1.5e-7) ----------------
__device__ __forceinline__ float gelu_f(float v) {
    float ax = fabsf(v) * 0.70710678118654752f;
    float t = 1.f / (1.f + 0.3275911f * ax);
    float poly = ((((1.061405429f * t - 1.453152027f) * t + 1.421413741f) * t -
                   0.284496736f) * t + 0.254829592f) * t;
    float erf_ax = 1.f - poly * __expf(-ax * ax);
    float erfv = (v < 0.f) ? -erf_ax : erf_ax;
    return 0.5f * v * (1.f + erfv);
}

// ---------------- reg-staged GEMM (M-masked; used for ragged-M embed gemms) ----------------
__global__ __launch_bounds__(256) void gemm_k(
    const __hip_bfloat16* __restrict__ A, const __hip_bfloat16* __restrict__ B,
    const float* __restrict__ bias, float* __restrict__ Cf, int M, int N, int K) {
    __shared__ float4 As4[1024];
    __shared__ float4 Bs4[1024];
    int tid = threadIdx.x;
    int lane = tid & 63, wid = tid >> 6;
    int wm = wid & 1, wn = wid >> 1;
    int mBase = blockIdx.x * 128, nBase = blockIdx.y * 128;
    const float4 fzero = {0.f, 0.f, 0.f, 0.f};
    f32x4 acc[4][4];
#pragma unroll
    for (int i = 0; i < 4; ++i)
#pragma unroll
        for (int j = 0; j < 4; ++j) {
            f32x4 z = {0.f, 0.f, 0.f, 0.f};
            acc[i][j] = z;
        }
    bf16x8* AsV = reinterpret_cast<bf16x8*>(As4);
    bf16x8* BsV = reinterpret_cast<bf16x8*>(Bs4);

    for (int k0 = 0; k0 < K; k0 += 64) {
#pragma unroll
        for (int i = 0; i < 4; ++i) {
            int cid = i * 256 + tid;
            int r = cid >> 3, c = cid & 7;
            int sidx = r * 8 + (c ^ (r & 7));
            int gr = mBase + r;
            float4 va = fzero;
            if (gr < M)
                va = *reinterpret_cast<const float4*>(A + (size_t)gr * K + k0 + c * 8);
            As4[sidx] = va;
            int gn = nBase + r;
            Bs4[sidx] = *reinterpret_cast<const float4*>(B + (size_t)gn * K + k0 + c * 8);
        }
        __syncthreads();
#pragma unroll
        for (int kk = 0; kk < 2; ++kk) {
            bf16x8 a[4], b[4];
            int ccol = kk * 4 + (lane >> 4);
#pragma unroll
            for (int f = 0; f < 4; ++f) {
                int ra = wm * 64 + f * 16 + (lane & 15);
                a[f] = AsV[ra * 8 + (ccol ^ (ra & 7))];
                int rb = wn * 64 + f * 16 + (lane & 15);
                b[f] = BsV[rb * 8 + (ccol ^ (rb & 7))];
            }
#pragma unroll
            for (int fm = 0; fm < 4; ++fm)
#pragma unroll
                for (int fn = 0; fn < 4; ++fn)
                    acc[fm][fn] = __builtin_amdgcn_mfma_f32_16x16x32_bf16(
                        a[fm], b[fn], acc[fm][fn], 0, 0, 0);
        }
        __syncthreads();
    }

    int colBase = nBase + wn * 64;
#pragma unroll
    for (int fm = 0; fm < 4; ++fm) {
        int row0 = mBase + wm * 64 + fm * 16 + (lane >> 4) * 4;
#pragma unroll
        for (int fn = 0; fn < 4; ++fn) {
            int col = colBase + fn * 16 + (lane & 15);
            float bv = bias ? bias[col] : 0.f;
#pragma unroll
            for (int j = 0; j < 4; ++j) {
                int row = row0 + j;
                if (row >= M) continue;
                Cf[(size_t)row * N + col] = acc[fm][fn][j] + bv;
            }
        }
    }
}

// ---------------- gload_lds double-buffered 2-phase GEMM ----------------
// C = A[M][K] @ B[N][K]^T + bias, M % 128 == 0, K % 64 == 0.
// modes: 0 = bf16 out; 1 = gelu->bf16; 2 = x+=v, h=LN(x); 3 = x+=v, h=bf16(x)
#define G2_BF16 0
#define G2_GELU 1
#define G2_ADD_LN 2
#define G2_ADD_BF16 3

template <int MODE>
__global__ __launch_bounds__(256) void gemm2_k(
    const __hip_bfloat16* __restrict__ A, const __hip_bfloat16* __restrict__ B,
    const float* __restrict__ bias, float* __restrict__ x,
    const float* __restrict__ lns, const float* __restrict__ lnb,
    __hip_bfloat16* __restrict__ hout, int N, int K) {
    __shared__ __align__(16) __hip_bfloat16 sA[2][128 * 64];
    __shared__ __align__(16) __hip_bfloat16 sB[2][128 * 64];
    __shared__ float redS[2][128];
    __shared__ float redS2[2][128];
    int tid = threadIdx.x;
    int lane = tid & 63, wid = tid >> 6;
    int wm = wid & 1, wn = wid >> 1;
    int mBase = blockIdx.x * 128, nBase = blockIdx.y * 128;
    f32x4 acc[4][4];
#pragma unroll
    for (int i = 0; i < 4; ++i)
#pragma unroll
        for (int j = 0; j < 4; ++j) {
            f32x4 z = {0.f, 0.f, 0.f, 0.f};
            acc[i][j] = z;
        }

    auto stage = [&](int buf, int k0) {
#pragma unroll
        for (int i = 0; i < 4; ++i) {
            int cid = i * 256 + tid;
            int row = cid >> 3, slotS = cid & 7;
            int slotG = slotS ^ (row & 7);
            const __hip_bfloat16* ga = A + (size_t)(mBase + row) * K + k0 + slotG * 8;
            const __hip_bfloat16* gb = B + (size_t)(nBase + row) * K + k0 + slotG * 8;
            __hip_bfloat16* la = &sA[buf][(cid & ~63) * 8];
            __hip_bfloat16* lb = &sB[buf][(cid & ~63) * 8];
            __builtin_amdgcn_global_load_lds((gbl_t*)ga, (lds_t*)la, 16, 0, 0);
            __builtin_amdgcn_global_load_lds((gbl_t*)gb, (lds_t*)lb, 16, 0, 0);
        }
    };

    int nt = K >> 6;
    stage(0, 0);
    int cur = 0;
    for (int t = 0; t < nt; ++t) {
        if (t + 1 < nt) {
            stage(cur ^ 1, (t + 1) << 6);
            asm volatile("s_waitcnt vmcnt(8)" ::: "memory");
        } else {
            asm volatile("s_waitcnt vmcnt(0)" ::: "memory");
        }
        __builtin_amdgcn_s_barrier();
        __builtin_amdgcn_sched_barrier(0);
        const bf16x8* AsV = reinterpret_cast<const bf16x8*>(sA[cur]);
        const bf16x8* BsV = reinterpret_cast<const bf16x8*>(sB[cur]);
#pragma unroll
        for (int kk = 0; kk < 2; ++kk) {
            bf16x8 a[4], b[4];
            int kvec = kk * 4 + (lane >> 4);
#pragma unroll
            for (int f = 0; f < 4; ++f) {
                int ra = wm * 64 + f * 16 + (lane & 15);
                a[f] = AsV[ra * 8 + (kvec ^ (ra & 7))];
                int rb = wn * 64 + f * 16 + (lane & 15);
                b[f] = BsV[rb * 8 + (kvec ^ (rb & 7))];
            }
#pragma unroll
            for (int fm = 0; fm < 4; ++fm)
#pragma unroll
                for (int fn = 0; fn < 4; ++fn)
                    acc[fm][fn] = __builtin_amdgcn_mfma_f32_16x16x32_bf16(
                        a[fm], b[fn], acc[fm][fn], 0, 0, 0);
        }
        __builtin_amdgcn_s_barrier();
        cur ^= 1;
    }

    if (MODE == G2_BF16 || MODE == G2_GELU) {
        int colBase = nBase + wn * 64;
#pragma unroll
        for (int fm = 0; fm < 4; ++fm) {
            int row0 = mBase + wm * 64 + fm * 16 + (lane >> 4) * 4;
#pragma unroll
            for (int fn = 0; fn < 4; ++fn) {
                int col = colBase + fn * 16 + (lane & 15);
                float bv = bias[col];
#pragma unroll
                for (int j = 0; j < 4; ++j) {
                    float v = acc[fm][fn][j] + bv;
                    if (MODE == G2_GELU) v = gelu_f(v);
                    hout[(size_t)(row0 + j) * N + col] = __float2bfloat16(v);
                }
            }
        }
    } else {
        // N == 128, nBase == 0: residual add + LN / bf16 copy
#pragma unroll
        for (int fm = 0; fm < 4; ++fm) {
            int rl0 = wm * 64 + fm * 16 + (lane >> 4) * 4;
#pragma unroll
            for (int fn = 0; fn < 4; ++fn) {
                int col = wn * 64 + fn * 16 + (lane & 15);
                float bv = bias[col];
#pragma unroll
                for (int j = 0; j < 4; ++j) {
                    size_t off = (size_t)(mBase + rl0 + j) * 128 + col;
                    float v = acc[fm][fn][j] + bv + x[off];
                    x[off] = v;
                    acc[fm][fn][j] = v;
                }
            }
        }
        if (MODE == G2_ADD_BF16) {
#pragma unroll
            for (int fm = 0; fm < 4; ++fm) {
                int rl0 = wm * 64 + fm * 16 + (lane >> 4) * 4;
#pragma unroll
                for (int fn = 0; fn < 4; ++fn) {
                    int col = wn * 64 + fn * 16 + (lane & 15);
#pragma unroll
                    for (int j = 0; j < 4; ++j)
                        hout[(size_t)(mBase + rl0 + j) * 128 + col] =
                            __float2bfloat16(acc[fm][fn][j]);
                }
            }
        } else {
            // LN over rows distributed in MFMA layout
#pragma unroll
            for (int fm = 0; fm < 4; ++fm) {
#pragma unroll
                for (int j = 0; j < 4; ++j) {
                    float s1 = 0.f, s2 = 0.f;
#pragma unroll
                    for (int fn = 0; fn < 4; ++fn) {
                        float v = acc[fm][fn][j];
                        s1 += v;
                        s2 += v * v;
                    }
#pragma unroll
                    for (int off = 1; off < 16; off <<= 1) {
                        s1 += __shfl_xor(s1, off, 64);
                        s2 += __shfl_xor(s2, off, 64);
                    }
                    if ((lane & 15) == 0) {
                        int rl = wm * 64 + fm * 16 + (lane >> 4) * 4 + j;
                        redS[wn][rl] = s1;
                        redS2[wn][rl] = s2;
                    }
                }
            }
            __syncthreads();
#pragma unroll
            for (int fm = 0; fm < 4; ++fm) {
                int rl0 = wm * 64 + fm * 16 + (lane >> 4) * 4;
#pragma unroll
                for (int j = 0; j < 4; ++j) {
                    int rl = rl0 + j;
                    float mean = (redS[0][rl] + redS[1][rl]) * (1.f / 128.f);
                    float var = (redS2[0][rl] + redS2[1][rl]) * (1.f / 128.f) - mean * mean;
                    float inv = rsqrtf(var + 1e-5f);
#pragma unroll
                    for (int fn = 0; fn < 4; ++fn) {
                        int col = wn * 64 + fn * 16 + (lane & 15);
                        float c = (acc[fm][fn][j] - mean) * inv;
                        hout[(size_t)(mBase + rl) * 128 + col] =
                            __float2bfloat16(c * lns[col] + lnb[col]);
                    }
                }
            }
        }
    }
}

// ---------------- attention: wave per group, groups contiguous ----------------
__global__ __launch_bounds__(256) void attn_k(
    const __hip_bfloat16* __restrict__ qkv, const int* __restrict__ starts,
    const int* __restrict__ cnt, __hip_bfloat16* __restrict__ o) {
    __shared__ float sc[4][4][MAXL];
    __shared__ float sinv[4][4];
    int wid = threadIdx.x >> 6, lane = threadIdx.x & 63;
    int node = blockIdx.x * 4 + wid;
    if (node >= NNODES) return;
    int st = starts[node];
    int len = cnt[node];
    if (len <= 0) return;
    if (len > MAXL) len = MAXL;
    const float scale = 0.17677669529663687f;
    int h01 = lane >> 5;
    for (int qi = 0; qi < len; ++qi) {
        const __hip_bfloat16* qrow = qkv + (size_t)(st + qi) * 384;
        float q0 = __bfloat162float(qrow[lane]);
        float q1 = __bfloat162float(qrow[64 + lane]);
        for (int j = 0; j < len; ++j) {
            const __hip_bfloat16* krow = qkv + (size_t)(st + j) * 384 + 128;
            float p0 = q0 * __bfloat162float(krow[lane]);
            float p1 = q1 * __bfloat162float(krow[64 + lane]);
#pragma unroll
            for (int off = 16; off; off >>= 1) {
                p0 += __shfl_xor(p0, off, 64);
                p1 += __shfl_xor(p1, off, 64);
            }
            if ((lane & 31) == 0) {
                sc[wid][h01][j] = p0 * scale;
                sc[wid][2 + h01][j] = p1 * scale;
            }
        }
        int hh = lane >> 4, li = lane & 15;
        float mx = -1e30f;
        for (int j = li; j < len; j += 16) mx = fmaxf(mx, sc[wid][hh][j]);
#pragma unroll
        for (int off = 8; off; off >>= 1) mx = fmaxf(mx, __shfl_xor(mx, off, 64));
        float ssum = 0.f;
        for (int j = li; j < len; j += 16) {
            float e = __expf(sc[wid][hh][j] - mx);
            sc[wid][hh][j] = e;
            ssum += e;
        }
#pragma unroll
        for (int off = 8; off; off >>= 1) ssum += __shfl_xor(ssum, off, 64);
        if (li == 0) sinv[wid][hh] = 1.f / ssum;
        float a0 = 0.f, a1 = 0.f;
        for (int j = 0; j < len; ++j) {
            const __hip_bfloat16* vrow = qkv + (size_t)(st + j) * 384 + 256;
            a0 += sc[wid][h01][j] * __bfloat162float(vrow[lane]);
            a1 += sc[wid][2 + h01][j] * __bfloat162float(vrow[64 + lane]);
        }
        __hip_bfloat16* orow = o + (size_t)(st + qi) * 128;
        orow[lane] = __float2bfloat16(a0 * sinv[wid][h01]);
        orow[64 + lane] = __float2bfloat16(a1 * sinv[wid][2 + h01]);
    }
}

// ---------------- p1 GEMM + relu + head (logits+softmax) ----------------
__global__ __launch_bounds__(256) void p1head_k(
    const __hip_bfloat16* __restrict__ A, const __hip_bfloat16* __restrict__ B,
    const float* __restrict__ bias, const float* __restrict__ p2w,
    const float* __restrict__ p2b, const int* __restrict__ order,
    float* __restrict__ out) {
    __shared__ __align__(16) char smem[65536];
    __shared__ float p2s[640];
    __shared__ float p2bs[5];
    float4* As4 = (float4*)smem;
    float4* Bs4 = (float4*)(smem + 16384);
    float* rowbuf = (float*)smem;
    int tid = threadIdx.x;
    for (int i = tid; i < 640; i += 256) p2s[i] = p2w[i];
    if (tid < 5) p2bs[tid] = p2b[tid];
    int lane = tid & 63, wid = tid >> 6;
    int wm = wid & 1, wn = wid >> 1;
    int mBase = blockIdx.x * 128;
    f32x4 acc[4][4];
#pragma unroll
    for (int i = 0; i < 4; ++i)
#pragma unroll
        for (int j = 0; j < 4; ++j) {
            f32x4 z = {0.f, 0.f, 0.f, 0.f};
            acc[i][j] = z;
        }
    bf16x8* AsV = reinterpret_cast<bf16x8*>(As4);
    bf16x8* BsV = reinterpret_cast<bf16x8*>(Bs4);
    for (int k0 = 0; k0 < 128; k0 += 64) {
#pragma unroll
        for (int i = 0; i < 4; ++i) {
            int cid = i * 256 + tid;
            int r = cid >> 3, c = cid & 7;
            int sidx = r * 8 + (c ^ (r & 7));
            As4[sidx] = *reinterpret_cast<const float4*>(A + (size_t)(mBase + r) * 128 + k0 + c * 8);
            Bs4[sidx] = *reinterpret_cast<const float4*>(B + (size_t)r * 128 + k0 + c * 8);
        }
        __syncthreads();
#pragma unroll
        for (int kk = 0; kk < 2; ++kk) {
            bf16x8 a[4], bb[4];
            int ccol = kk * 4 + (lane >> 4);
#pragma unroll
            for (int f = 0; f < 4; ++f) {
                int ra = wm * 64 + f * 16 + (lane & 15);
                a[f] = AsV[ra * 8 + (ccol ^ (ra & 7))];
                int rb = wn * 64 + f * 16 + (lane & 15);
                bb[f] = BsV[rb * 8 + (ccol ^ (rb & 7))];
            }
#pragma unroll
            for (int fm = 0; fm < 4; ++fm)
#pragma unroll
                for (int fn = 0; fn < 4; ++fn)
                    acc[fm][fn] = __builtin_amdgcn_mfma_f32_16x16x32_bf16(
                        a[fm], bb[fn], acc[fm][fn], 0, 0, 0);
        }
        __syncthreads();
    }
#pragma unroll
    for (int fm = 0; fm < 4; ++fm) {
        int rl0 = wm * 64 + fm * 16 + (lane >> 4) * 4;
#pragma unroll
        for (int fn = 0; fn < 4; ++fn) {
            int col = wn * 64 + fn * 16 + (lane & 15);
            float bv = bias[col];
#pragma unroll
            for (int j = 0; j < 4; ++j) {
                int rl = rl0 + j;
                rowbuf[rl * 128 + (col ^ ((rl & 7) << 2))] = fmaxf(acc[fm][fn][j] + bv, 0.f);
            }
        }
    }
    __syncthreads();
    int row = tid >> 1, half = tid & 1;
    int swz = (row & 7) << 2;
    float lg[5] = {0.f, 0.f, 0.f, 0.f, 0.f};
    for (int i = 0; i < 64; ++i) {
        int col = half * 64 + i;
        float rv = rowbuf[row * 128 + (col ^ swz)];
#pragma unroll
        for (int k = 0; k < 5; ++k) lg[k] += rv * p2s[k * 128 + col];
    }
#pragma unroll
    for (int k = 0; k < 5; ++k) lg[k] += __shfl_xor(lg[k], 1, 64);
    if (half == 0) {
        float mx = -1e30f;
#pragma unroll
        for (int k = 0; k < 5; ++k) {
            lg[k] += p2bs[k];
            mx = fmaxf(mx, lg[k]);
        }
        float e[5], ssum = 0.f;
#pragma unroll
        for (int k = 0; k < 5; ++k) {
            e[k] = __expf(lg[k] - mx);
            ssum += e[k];
        }
        float si = 1.f / ssum;
        int t = order[mBase + row];
#pragma unroll
        for (int k = 0; k < 5; ++k) out[(size_t)t * 5 + k] = e[k] * si;
    }
}

// ---------------- host launch ----------------

extern "C" void kernel_launch(void* const* d_in, const int* in_sizes, int n_in,
                              void* d_out, int out_size, void* d_ws, size_t ws_size,
                              hipStream_t stream) {
    const int* src = (const int*)d_in[0];
    const int* dst = (const int*)d_in[1];
    const int* neg = (const int*)d_in[2];
    const int* eidx = (const int*)d_in[3];
    const float* ts = (const float*)d_in[4];
    const float* node_feats = (const float*)d_in[5];
    const float* edge_feats = (const float*)d_in[6];
    const float* node_lin_w = (const float*)d_in[7];
    const float* node_lin_b = (const float*)d_in[8];
    const float* edge_lin_w = (const float*)d_in[9];
    const float* edge_lin_b = (const float*)d_in[10];
    const float* time_w = (const float*)d_in[11];
    const float* time_b = (const float*)d_in[12];
    const float* tok_w = (const float*)d_in[13];
    const float* tok_b = (const float*)d_in[14];
    const float* qkv_w = (const float*)d_in[15];
    const float* qkv_b = (const float*)d_in[16];
    const float* attn_w = (const float*)d_in[17];
    const float* attn_b = (const float*)d_in[18];
    const float* ln1_s = (const float*)d_in[19];
    const float* ln1_b = (const float*)d_in[20];
    const float* ln2_s = (const float*)d_in[21];
    const float* ln2_b = (const float*)d_in[22];
    const float* ff1_w = (const float*)d_in[23];
    const float* ff1_b = (const float*)d_in[24];
    const float* ff2_w = (const float*)d_in[25];
    const float* ff2_b = (const float*)d_in[26];
    const float* p1_w = (const float*)d_in[27];
    const float* p1_b = (const float*)d_in[28];
    const float* p2_w = (const float*)d_in[29];
    const float* p2_b = (const float*)d_in[30];
    float* out = (float*)d_out;

    char* w = (char*)d_ws;
    auto alloc = [&](size_t bytes) {
        char* p = w;
        w += (bytes + 255) & ~(size_t)255;
        return p;
    };
    float* x = (float*)alloc((size_t)NTOK * 128 * 4);
    __hip_bfloat16* h = (__hip_bfloat16*)alloc((size_t)NTOK * 128 * 2);
    char* big = alloc((size_t)NTOK * 512 * 2);   // qkvb+ob / ub
    __hip_bfloat16* qkvb = (__hip_bfloat16*)big;
    __hip_bfloat16* ob = (__hip_bfloat16*)(big + (size_t)NTOK * 384 * 2);
    __hip_bfloat16* ub = (__hip_bfloat16*)big;
    float* P12 = (float*)alloc((size_t)NNODES * 256 * 4);
    float* E = (float*)alloc((size_t)NB * 128 * 4);
    __hip_bfloat16* Aemb = (__hip_bfloat16*)alloc((size_t)NB * 192 * 2);
    __hip_bfloat16* nfb = (__hip_bfloat16*)alloc((size_t)NNODES * 128 * 2);
    __hip_bfloat16* A12 = (__hip_bfloat16*)alloc(256 * 128 * 2);
    __hip_bfloat16* AE = (__hip_bfloat16*)alloc(128 * 192 * 2);
    float* bfold = (float*)alloc(128 * 4);
    __hip_bfloat16* qkvwb = (__hip_bfloat16*)alloc(2 * 384 * 128 * 2);
    __hip_bfloat16* attnwb = (__hip_bfloat16*)alloc(2 * 128 * 128 * 2);
    __hip_bfloat16* ff1wb = (__hip_bfloat16*)alloc(2 * 512 * 128 * 2);
    __hip_bfloat16* ff2wb = (__hip_bfloat16*)alloc(2 * 128 * 512 * 2);
    __hip_bfloat16* p1wb = (__hip_bfloat16*)alloc(128 * 128 * 2);
    int* cnt = (int*)alloc(NNODES * 4);
    int* starts = (int*)alloc(NNODES * 4);
    int* cursor = (int*)alloc(NNODES * 4);
    int* order = (int*)alloc(NTOK * 4);

    hipMemsetAsync(cnt, 0, NNODES * 4, stream);
    hipMemsetAsync(cursor, 0, NNODES * 4, stream);

    auto cvt = [&](const float* in, __hip_bfloat16* outp, int n) {
        int blocks = (n + 255) / 256;
        if (blocks > 2048) blocks = 2048;
        convert_k<<<blocks, 256, 0, stream>>>(in, outp, n);
    };
    cvt(node_feats, nfb, NNODES * 128);
    cvt(qkv_w, qkvwb, 2 * 384 * 128);
    cvt(attn_w, attnwb, 2 * 128 * 128);
    cvt(ff1_w, ff1wb, 2 * 512 * 128);
    cvt(ff2_w, ff2wb, 2 * 128 * 512);
    cvt(p1_w, p1wb, 128 * 128);

    fold12_k<<<128, 256, 0, stream>>>(tok_w, node_lin_w, A12);
    foldE_k<<<96, 256, 0, stream>>>(tok_w, edge_lin_w, AE);
    foldb_k<<<1, 128, 0, stream>>>(tok_w, tok_b, node_lin_b, edge_lin_b, bfold);

    count_k<<<(NTOK + 255) / 256, 256, 0, stream>>>(src, dst, neg, cnt);
    scan_k<<<1, 256, 0, stream>>>(cnt, starts, NNODES);
    scatter_k<<<(NTOK + 255) / 256, 256, 0, stream>>>(src, dst, neg, starts, cursor, order);

    aemb_k<<<(NB * 192 + 255) / 256, 256, 0, stream>>>(eidx, ts, edge_feats, time_w, time_b, Aemb);

    gemm_k<<<dim3(157, 2), 256, 0, stream>>>(nfb, A12, nullptr, P12, NNODES, 256, 128);
    gemm_k<<<dim3(256, 1), 256, 0, stream>>>(Aemb, AE, bfold, E, NB, 128, 192);
    asm_emb_k<<<NTOK / 4, 256, 0, stream>>>(order, src, dst, neg, P12, E,
                                            ln1_s, ln1_b, x, h);

    const int gm = NTOK / 128;  // 768
    for (int l = 0; l < 2; ++l) {
        gemm2_k<G2_BF16><<<dim3(gm, 3), 256, 0, stream>>>(
            h, qkvwb + (size_t)l * 384 * 128, qkv_b + l * 384,
            nullptr, nullptr, nullptr, qkvb, 384, 128);
        attn_k<<<(NNODES + 3) / 4, 256, 0, stream>>>(qkvb, starts, cnt, ob);
        gemm2_k<G2_ADD_LN><<<dim3(gm, 1), 256, 0, stream>>>(
            ob, attnwb + (size_t)l * 128 * 128, attn_b + l * 128,
            x, ln2_s + l * 128, ln2_b + l * 128, h, 128, 128);
        gemm2_k<G2_GELU><<<dim3(gm, 4), 256, 0, stream>>>(
            h, ff1wb + (size_t)l * 512 * 128, ff1_b + l * 512,
            nullptr, nullptr, nullptr, ub, 512, 128);
        if (l == 0)
            gemm2_k<G2_ADD_LN><<<dim3(gm, 1), 256, 0, stream>>>(
                ub, ff2wb, ff2_b, x, ln1_s + 128, ln1_b + 128, h, 128, 512);
        else
            gemm2_k<G2_ADD_BF16><<<dim3(gm, 1), 256, 0, stream>>>(
                ub, ff2wb + (size_t)128 * 512, ff2_b + 128, x,
                nullptr, nullptr, h, 128, 512);
    }

    p1head_k<<<gm, 256, 0, stream>>>(h, p1wb, p1_b, p2_w, p2_b, order, out);
}

// Round 5
// 627.462 us; speedup vs baseline: 5.3991x; 1.4353x over previous
//
#include <hip/hip_runtime.h>
#include <hip/hip_bf16.h>
#include <math.h>

#define NB 32768
#define NTOK (3 * NB)
#define NNODES 20000
#define MAXL 64

typedef short bf16x8 __attribute__((ext_vector_type(8)));
typedef float f32x4 __attribute__((ext_vector_type(4)));

typedef __attribute__((address_space(3))) void lds_t;
typedef const __attribute__((address_space(1))) void gbl_t;

__device__ __forceinline__ float b2f(short s) {
    unsigned int u = ((unsigned int)(unsigned short)s) << 16;
    union { unsigned int u; float f; } c;
    c.u = u;
    return c.f;
}

// ---------------- small setup kernels ----------------

__global__ void convert_k(const float* __restrict__ in, __hip_bfloat16* __restrict__ out, int n) {
    int i = blockIdx.x * 256 + threadIdx.x;
    int stride = gridDim.x * 256;
    for (; i < n; i += stride) out[i] = __float2bfloat16(in[i]);
}

__global__ void fold12_k(const float* __restrict__ tok_w, const float* __restrict__ nl_w,
                         __hip_bfloat16* __restrict__ A12) {
    int idx = blockIdx.x * 256 + threadIdx.x;
    if (idx >= 256 * 128) return;
    int n = idx >> 7, f = idx & 127;
    const float* tw = (n < 128) ? (tok_w + n * 512) : (tok_w + (n - 128) * 512 + 128);
    float acc = 0.f;
    for (int c = 0; c < 128; ++c) acc += tw[c] * nl_w[c * 128 + f];
    A12[idx] = __float2bfloat16(acc);
}

__global__ void foldE_k(const float* __restrict__ tok_w, const float* __restrict__ el_w,
                        __hip_bfloat16* __restrict__ AE) {
    int idx = blockIdx.x * 256 + threadIdx.x;
    if (idx >= 128 * 192) return;
    int d = idx / 192, j = idx % 192;
    float acc;
    if (j < 64) {
        acc = 0.f;
        for (int c = 0; c < 128; ++c) acc += tok_w[d * 512 + 256 + c] * el_w[c * 64 + j];
    } else {
        acc = tok_w[d * 512 + 384 + (j - 64)];
    }
    AE[idx] = __float2bfloat16(acc);
}

__global__ void foldb_k(const float* __restrict__ tok_w, const float* __restrict__ tok_b,
                        const float* __restrict__ nl_b, const float* __restrict__ el_b,
                        float* __restrict__ bf) {
    int d = threadIdx.x;
    if (d >= 128) return;
    float acc = tok_b[d];
    for (int c = 0; c < 128; ++c)
        acc += (tok_w[d * 512 + c] + tok_w[d * 512 + 128 + c]) * nl_b[c];
    for (int c = 0; c < 128; ++c)
        acc += tok_w[d * 512 + 256 + c] * el_b[c];
    bf[d] = acc;
}

__device__ __forceinline__ int self_node(int t, const int* src, const int* dst, const int* neg) {
    if (t < NB) return src[t];
    if (t < 2 * NB) return dst[t - NB];
    return neg[t - 2 * NB];
}

__global__ void count_k(const int* __restrict__ src, const int* __restrict__ dst,
                        const int* __restrict__ neg, int* __restrict__ cnt) {
    int t = blockIdx.x * 256 + threadIdx.x;
    if (t >= NTOK) return;
    atomicAdd(&cnt[self_node(t, src, dst, neg)], 1);
}

// single-block 1024-thread exclusive scan of cnt -> starts
__global__ __launch_bounds__(1024) void scan_k(const int* __restrict__ cnt,
                                               int* __restrict__ starts) {
    __shared__ int ps[1024];
    int t = threadIdx.x;
    const int PER = 20;  // 1024*20 >= 20000
    int base = t * PER;
    int loc[PER];
    int s = 0;
#pragma unroll
    for (int k = 0; k < PER; ++k) {
        int i = base + k;
        int v = (i < NNODES) ? cnt[i] : 0;
        loc[k] = s;
        s += v;
    }
    ps[t] = s;
    __syncthreads();
    for (int off = 1; off < 1024; off <<= 1) {
        int v = (t >= off) ? ps[t - off] : 0;
        __syncthreads();
        ps[t] += v;
        __syncthreads();
    }
    int offv = (t > 0) ? ps[t - 1] : 0;
#pragma unroll
    for (int k = 0; k < PER; ++k) {
        int i = base + k;
        if (i < NNODES) starts[i] = offv + loc[k];
    }
}

__global__ void scatter_k(const int* __restrict__ src, const int* __restrict__ dst,
                          const int* __restrict__ neg, const int* __restrict__ starts,
                          int* __restrict__ cursor, int* __restrict__ order) {
    int t = blockIdx.x * 256 + threadIdx.x;
    if (t >= NTOK) return;
    int node = self_node(t, src, dst, neg);
    int p = atomicAdd(&cursor[node], 1);
    order[starts[node] + p] = t;
}

__global__ void aemb_k(const int* __restrict__ eidx, const float* __restrict__ ts,
                       const float* __restrict__ ef, const float* __restrict__ tw,
                       const float* __restrict__ tb, __hip_bfloat16* __restrict__ Aemb) {
    int idx = blockIdx.x * 256 + threadIdx.x;
    if (idx >= NB * 192) return;
    int m = idx / 192, j = idx % 192;
    float v;
    if (j < 64) v = ef[(size_t)eidx[m] * 64 + j];
    else { int c = j - 64; v = cosf(ts[m] * tw[c] + tb[c]); }
    Aemb[idx] = __float2bfloat16(v);
}

// x[p] = relu(gathered sum) in SORTED order; h[p] = LN1_l0(x[p])
__global__ __launch_bounds__(256) void asm_emb_k(
    const int* __restrict__ order, const int* __restrict__ src, const int* __restrict__ dst,
    const int* __restrict__ neg, const float* __restrict__ P12, const float* __restrict__ E,
    const float* __restrict__ s, const float* __restrict__ b,
    float* __restrict__ x, __hip_bfloat16* __restrict__ h) {
    int p = blockIdx.x * 4 + (threadIdx.x >> 6);
    int lane = threadIdx.x & 63;
    int t = order[p];
    int m, self, other;
    if (t < NB) { m = t; self = src[m]; other = dst[m]; }
    else if (t < 2 * NB) { m = t - NB; self = dst[m]; other = src[m]; }
    else { m = t - 2 * NB; self = neg[m]; other = src[m]; }
    int d0 = lane, d1 = lane + 64;
    float v0 = P12[(size_t)self * 256 + d0] + P12[(size_t)other * 256 + 128 + d0] +
               E[(size_t)m * 128 + d0];
    float v1 = P12[(size_t)self * 256 + d1] + P12[(size_t)other * 256 + 128 + d1] +
               E[(size_t)m * 128 + d1];
    v0 = fmaxf(v0, 0.f);
    v1 = fmaxf(v1, 0.f);
    float sum = v0 + v1;
#pragma unroll
    for (int off = 32; off; off >>= 1) sum += __shfl_xor(sum, off, 64);
    float mean = sum * (1.f / 128.f);
    float c0 = v0 - mean, c1 = v1 - mean;
    float vs = c0 * c0 + c1 * c1;
#pragma unroll
    for (int off = 32; off; off >>= 1) vs += __shfl_xor(vs, off, 64);
    float inv = rsqrtf(vs * (1.f / 128.f) + 1e-5f);
    x[(size_t)p * 128 + d0] = v0;
    x[(size_t)p * 128 + d1] = v1;
    h[(size_t)p * 128 + d0] = __float2bfloat16(c0 * inv * s[d0] + b[d0]);
    h[(size_t)p * 128 + d1] = __float2bfloat16(c1 * inv * s[d1] + b[d1]);
}

// ---------------- fast gelu (A&S 7.1.26 erf, |err|<1.5e-7) ----------------
__device__ __forceinline__ float gelu_f(float v) {
    float ax = fabsf(v) * 0.70710678118654752f;
    float t = 1.f / (1.f + 0.3275911f * ax);
    float poly = ((((1.061405429f * t - 1.453152027f) * t + 1.421413741f) * t -
                   0.284496736f) * t + 0.254829592f) * t;
    float erf_ax = 1.f - poly * __expf(-ax * ax);
    float erfv = (v < 0.f) ? -erf_ax : erf_ax;
    return 0.5f * v * (1.f + erfv);
}

// ---------------- reg-staged GEMM (M-masked; used for ragged-M embed gemms) ----------------
__global__ __launch_bounds__(256) void gemm_k(
    const __hip_bfloat16* __restrict__ A, const __hip_bfloat16* __restrict__ B,
    const float* __restrict__ bias, float* __restrict__ Cf, int M, int N, int K) {
    __shared__ float4 As4[1024];
    __shared__ float4 Bs4[1024];
    int tid = threadIdx.x;
    int lane = tid & 63, wid = tid >> 6;
    int wm = wid & 1, wn = wid >> 1;
    int mBase = blockIdx.x * 128, nBase = blockIdx.y * 128;
    const float4 fzero = {0.f, 0.f, 0.f, 0.f};
    f32x4 acc[4][4];
#pragma unroll
    for (int i = 0; i < 4; ++i)
#pragma unroll
        for (int j = 0; j < 4; ++j) {
            f32x4 z = {0.f, 0.f, 0.f, 0.f};
            acc[i][j] = z;
        }
    bf16x8* AsV = reinterpret_cast<bf16x8*>(As4);
    bf16x8* BsV = reinterpret_cast<bf16x8*>(Bs4);

    for (int k0 = 0; k0 < K; k0 += 64) {
#pragma unroll
        for (int i = 0; i < 4; ++i) {
            int cid = i * 256 + tid;
            int r = cid >> 3, c = cid & 7;
            int sidx = r * 8 + (c ^ (r & 7));
            int gr = mBase + r;
            float4 va = fzero;
            if (gr < M)
                va = *reinterpret_cast<const float4*>(A + (size_t)gr * K + k0 + c * 8);
            As4[sidx] = va;
            int gn = nBase + r;
            Bs4[sidx] = *reinterpret_cast<const float4*>(B + (size_t)gn * K + k0 + c * 8);
        }
        __syncthreads();
#pragma unroll
        for (int kk = 0; kk < 2; ++kk) {
            bf16x8 a[4], b[4];
            int ccol = kk * 4 + (lane >> 4);
#pragma unroll
            for (int f = 0; f < 4; ++f) {
                int ra = wm * 64 + f * 16 + (lane & 15);
                a[f] = AsV[ra * 8 + (ccol ^ (ra & 7))];
                int rb = wn * 64 + f * 16 + (lane & 15);
                b[f] = BsV[rb * 8 + (ccol ^ (rb & 7))];
            }
#pragma unroll
            for (int fm = 0; fm < 4; ++fm)
#pragma unroll
                for (int fn = 0; fn < 4; ++fn)
                    acc[fm][fn] = __builtin_amdgcn_mfma_f32_16x16x32_bf16(
                        a[fm], b[fn], acc[fm][fn], 0, 0, 0);
        }
        __syncthreads();
    }

    int colBase = nBase + wn * 64;
#pragma unroll
    for (int fm = 0; fm < 4; ++fm) {
        int row0 = mBase + wm * 64 + fm * 16 + (lane >> 4) * 4;
#pragma unroll
        for (int fn = 0; fn < 4; ++fn) {
            int col = colBase + fn * 16 + (lane & 15);
            float bv = bias ? bias[col] : 0.f;
#pragma unroll
            for (int j = 0; j < 4; ++j) {
                int row = row0 + j;
                if (row >= M) continue;
                Cf[(size_t)row * N + col] = acc[fm][fn][j] + bv;
            }
        }
    }
}

// ---------------- single-stage K=128 GEMM (barrier-free inner loop) ----------------
#define G2_BF16 0
#define G2_GELU 1
#define G2_ADD_LN 2
#define G2_ADD_BF16 3

template <int MODE>
__global__ __launch_bounds__(256) void gemm3_k(
    const __hip_bfloat16* __restrict__ A, const __hip_bfloat16* __restrict__ B,
    const float* __restrict__ bias, float* __restrict__ x,
    const float* __restrict__ lns, const float* __restrict__ lnb,
    __hip_bfloat16* __restrict__ hout, int N) {
    __shared__ __align__(16) __hip_bfloat16 sA[128 * 128];
    __shared__ __align__(16) __hip_bfloat16 sB[128 * 128];
    __shared__ float redS[2][128];
    __shared__ float redS2[2][128];
    int tid = threadIdx.x;
    int lane = tid & 63, wid = tid >> 6;
    int wm = wid & 1, wn = wid >> 1;
    int mBase = blockIdx.x * 128, nBase = blockIdx.y * 128;
    f32x4 acc[4][4];
#pragma unroll
    for (int i = 0; i < 4; ++i)
#pragma unroll
        for (int j = 0; j < 4; ++j) {
            f32x4 z = {0.f, 0.f, 0.f, 0.f};
            acc[i][j] = z;
        }

    // stage entire 128x128 A and B tiles (K=128)
#pragma unroll
    for (int i = 0; i < 8; ++i) {
        int cid = i * 256 + tid;          // 0..2047 16B-vec index
        int row = cid >> 4, slotS = cid & 15;
        int slotG = slotS ^ (row & 15);
        const __hip_bfloat16* ga = A + (size_t)(mBase + row) * 128 + slotG * 8;
        const __hip_bfloat16* gb = B + (size_t)(nBase + row) * 128 + slotG * 8;
        __builtin_amdgcn_global_load_lds((gbl_t*)ga, (lds_t*)&sA[(cid & ~63) * 8], 16, 0, 0);
        __builtin_amdgcn_global_load_lds((gbl_t*)gb, (lds_t*)&sB[(cid & ~63) * 8], 16, 0, 0);
    }
    asm volatile("s_waitcnt vmcnt(0)" ::: "memory");
    __builtin_amdgcn_s_barrier();
    __builtin_amdgcn_sched_barrier(0);

    const bf16x8* AsV = reinterpret_cast<const bf16x8*>(sA);
    const bf16x8* BsV = reinterpret_cast<const bf16x8*>(sB);
#pragma unroll
    for (int kk = 0; kk < 4; ++kk) {
        bf16x8 a[4], b[4];
        int kvec = kk * 4 + (lane >> 4);
#pragma unroll
        for (int f = 0; f < 4; ++f) {
            int ra = wm * 64 + f * 16 + (lane & 15);
            a[f] = AsV[ra * 16 + (kvec ^ (ra & 15))];
            int rb = wn * 64 + f * 16 + (lane & 15);
            b[f] = BsV[rb * 16 + (kvec ^ (rb & 15))];
        }
#pragma unroll
        for (int fm = 0; fm < 4; ++fm)
#pragma unroll
            for (int fn = 0; fn < 4; ++fn)
                acc[fm][fn] = __builtin_amdgcn_mfma_f32_16x16x32_bf16(
                    a[fm], b[fn], acc[fm][fn], 0, 0, 0);
    }

    if (MODE == G2_BF16 || MODE == G2_GELU) {
        int colBase = nBase + wn * 64;
#pragma unroll
        for (int fm = 0; fm < 4; ++fm) {
            int row0 = mBase + wm * 64 + fm * 16 + (lane >> 4) * 4;
#pragma unroll
            for (int fn = 0; fn < 4; ++fn) {
                int col = colBase + fn * 16 + (lane & 15);
                float bv = bias[col];
#pragma unroll
                for (int j = 0; j < 4; ++j) {
                    float v = acc[fm][fn][j] + bv;
                    if (MODE == G2_GELU) v = gelu_f(v);
                    hout[(size_t)(row0 + j) * N + col] = __float2bfloat16(v);
                }
            }
        }
    } else {
#pragma unroll
        for (int fm = 0; fm < 4; ++fm) {
            int rl0 = wm * 64 + fm * 16 + (lane >> 4) * 4;
#pragma unroll
            for (int fn = 0; fn < 4; ++fn) {
                int col = wn * 64 + fn * 16 + (lane & 15);
                float bv = bias[col];
#pragma unroll
                for (int j = 0; j < 4; ++j) {
                    size_t off = (size_t)(mBase + rl0 + j) * 128 + col;
                    float v = acc[fm][fn][j] + bv + x[off];
                    x[off] = v;
                    acc[fm][fn][j] = v;
                }
            }
        }
        if (MODE == G2_ADD_BF16) {
#pragma unroll
            for (int fm = 0; fm < 4; ++fm) {
                int rl0 = wm * 64 + fm * 16 + (lane >> 4) * 4;
#pragma unroll
                for (int fn = 0; fn < 4; ++fn) {
                    int col = wn * 64 + fn * 16 + (lane & 15);
#pragma unroll
                    for (int j = 0; j < 4; ++j)
                        hout[(size_t)(mBase + rl0 + j) * 128 + col] =
                            __float2bfloat16(acc[fm][fn][j]);
                }
            }
        } else {
#pragma unroll
            for (int fm = 0; fm < 4; ++fm) {
#pragma unroll
                for (int j = 0; j < 4; ++j) {
                    float s1 = 0.f, s2 = 0.f;
#pragma unroll
                    for (int fn = 0; fn < 4; ++fn) {
                        float v = acc[fm][fn][j];
                        s1 += v;
                        s2 += v * v;
                    }
#pragma unroll
                    for (int off = 1; off < 16; off <<= 1) {
                        s1 += __shfl_xor(s1, off, 64);
                        s2 += __shfl_xor(s2, off, 64);
                    }
                    if ((lane & 15) == 0) {
                        int rl = wm * 64 + fm * 16 + (lane >> 4) * 4 + j;
                        redS[wn][rl] = s1;
                        redS2[wn][rl] = s2;
                    }
                }
            }
            __syncthreads();
#pragma unroll
            for (int fm = 0; fm < 4; ++fm) {
                int rl0 = wm * 64 + fm * 16 + (lane >> 4) * 4;
#pragma unroll
                for (int j = 0; j < 4; ++j) {
                    int rl = rl0 + j;
                    float mean = (redS[0][rl] + redS[1][rl]) * (1.f / 128.f);
                    float var = (redS2[0][rl] + redS2[1][rl]) * (1.f / 128.f) - mean * mean;
                    float inv = rsqrtf(var + 1e-5f);
#pragma unroll
                    for (int fn = 0; fn < 4; ++fn) {
                        int col = wn * 64 + fn * 16 + (lane & 15);
                        float c = (acc[fm][fn][j] - mean) * inv;
                        hout[(size_t)(mBase + rl) * 128 + col] =
                            __float2bfloat16(c * lns[col] + lnb[col]);
                    }
                }
            }
        }
    }
}

// ---------------- double-buffered GEMM for K=512 (ff2) ----------------
template <int MODE>
__global__ __launch_bounds__(256) void gemm2_k(
    const __hip_bfloat16* __restrict__ A, const __hip_bfloat16* __restrict__ B,
    const float* __restrict__ bias, float* __restrict__ x,
    const float* __restrict__ lns, const float* __restrict__ lnb,
    __hip_bfloat16* __restrict__ hout, int N, int K) {
    __shared__ __align__(16) __hip_bfloat16 sA[2][128 * 64];
    __shared__ __align__(16) __hip_bfloat16 sB[2][128 * 64];
    __shared__ float redS[2][128];
    __shared__ float redS2[2][128];
    int tid = threadIdx.x;
    int lane = tid & 63, wid = tid >> 6;
    int wm = wid & 1, wn = wid >> 1;
    int mBase = blockIdx.x * 128, nBase = blockIdx.y * 128;
    f32x4 acc[4][4];
#pragma unroll
    for (int i = 0; i < 4; ++i)
#pragma unroll
        for (int j = 0; j < 4; ++j) {
            f32x4 z = {0.f, 0.f, 0.f, 0.f};
            acc[i][j] = z;
        }

    auto stage = [&](int buf, int k0) {
#pragma unroll
        for (int i = 0; i < 4; ++i) {
            int cid = i * 256 + tid;
            int row = cid >> 3, slotS = cid & 7;
            int slotG = slotS ^ (row & 7);
            const __hip_bfloat16* ga = A + (size_t)(mBase + row) * K + k0 + slotG * 8;
            const __hip_bfloat16* gb = B + (size_t)(nBase + row) * K + k0 + slotG * 8;
            __hip_bfloat16* la = &sA[buf][(cid & ~63) * 8];
            __hip_bfloat16* lb = &sB[buf][(cid & ~63) * 8];
            __builtin_amdgcn_global_load_lds((gbl_t*)ga, (lds_t*)la, 16, 0, 0);
            __builtin_amdgcn_global_load_lds((gbl_t*)gb, (lds_t*)lb, 16, 0, 0);
        }
    };

    int nt = K >> 6;
    stage(0, 0);
    int cur = 0;
    for (int t = 0; t < nt; ++t) {
        if (t + 1 < nt) {
            stage(cur ^ 1, (t + 1) << 6);
            asm volatile("s_waitcnt vmcnt(8)" ::: "memory");
        } else {
            asm volatile("s_waitcnt vmcnt(0)" ::: "memory");
        }
        __builtin_amdgcn_s_barrier();
        __builtin_amdgcn_sched_barrier(0);
        const bf16x8* AsV = reinterpret_cast<const bf16x8*>(sA[cur]);
        const bf16x8* BsV = reinterpret_cast<const bf16x8*>(sB[cur]);
#pragma unroll
        for (int kk = 0; kk < 2; ++kk) {
            bf16x8 a[4], b[4];
            int kvec = kk * 4 + (lane >> 4);
#pragma unroll
            for (int f = 0; f < 4; ++f) {
                int ra = wm * 64 + f * 16 + (lane & 15);
                a[f] = AsV[ra * 8 + (kvec ^ (ra & 7))];
                int rb = wn * 64 + f * 16 + (lane & 15);
                b[f] = BsV[rb * 8 + (kvec ^ (rb & 7))];
            }
#pragma unroll
            for (int fm = 0; fm < 4; ++fm)
#pragma unroll
                for (int fn = 0; fn < 4; ++fn)
                    acc[fm][fn] = __builtin_amdgcn_mfma_f32_16x16x32_bf16(
                        a[fm], b[fn], acc[fm][fn], 0, 0, 0);
        }
        __builtin_amdgcn_s_barrier();
        cur ^= 1;
    }

#pragma unroll
    for (int fm = 0; fm < 4; ++fm) {
        int rl0 = wm * 64 + fm * 16 + (lane >> 4) * 4;
#pragma unroll
        for (int fn = 0; fn < 4; ++fn) {
            int col = wn * 64 + fn * 16 + (lane & 15);
            float bv = bias[col];
#pragma unroll
            for (int j = 0; j < 4; ++j) {
                size_t off = (size_t)(mBase + rl0 + j) * 128 + col;
                float v = acc[fm][fn][j] + bv + x[off];
                x[off] = v;
                acc[fm][fn][j] = v;
            }
        }
    }
    if (MODE == G2_ADD_BF16) {
#pragma unroll
        for (int fm = 0; fm < 4; ++fm) {
            int rl0 = wm * 64 + fm * 16 + (lane >> 4) * 4;
#pragma unroll
            for (int fn = 0; fn < 4; ++fn) {
                int col = wn * 64 + fn * 16 + (lane & 15);
#pragma unroll
                for (int j = 0; j < 4; ++j)
                    hout[(size_t)(mBase + rl0 + j) * 128 + col] =
                        __float2bfloat16(acc[fm][fn][j]);
            }
        }
    } else {
#pragma unroll
        for (int fm = 0; fm < 4; ++fm) {
#pragma unroll
            for (int j = 0; j < 4; ++j) {
                float s1 = 0.f, s2 = 0.f;
#pragma unroll
                for (int fn = 0; fn < 4; ++fn) {
                    float v = acc[fm][fn][j];
                    s1 += v;
                    s2 += v * v;
                }
#pragma unroll
                for (int off = 1; off < 16; off <<= 1) {
                    s1 += __shfl_xor(s1, off, 64);
                    s2 += __shfl_xor(s2, off, 64);
                }
                if ((lane & 15) == 0) {
                    int rl = wm * 64 + fm * 16 + (lane >> 4) * 4 + j;
                    redS[wn][rl] = s1;
                    redS2[wn][rl] = s2;
                }
            }
        }
        __syncthreads();
#pragma unroll
        for (int fm = 0; fm < 4; ++fm) {
            int rl0 = wm * 64 + fm * 16 + (lane >> 4) * 4;
#pragma unroll
            for (int j = 0; j < 4; ++j) {
                int rl = rl0 + j;
                float mean = (redS[0][rl] + redS[1][rl]) * (1.f / 128.f);
                float var = (redS2[0][rl] + redS2[1][rl]) * (1.f / 128.f) - mean * mean;
                float inv = rsqrtf(var + 1e-5f);
#pragma unroll
                for (int fn = 0; fn < 4; ++fn) {
                    int col = wn * 64 + fn * 16 + (lane & 15);
                    float c = (acc[fm][fn][j] - mean) * inv;
                    hout[(size_t)(mBase + rl) * 128 + col] =
                        __float2bfloat16(c * lns[col] + lnb[col]);
                }
            }
        }
    }
}

// ---------------- attention: wave per group, 4 queries in parallel ----------------
__global__ __launch_bounds__(256) void attn_k(
    const __hip_bfloat16* __restrict__ qkv, const int* __restrict__ starts,
    const int* __restrict__ cnt, __hip_bfloat16* __restrict__ o) {
    __shared__ float sc[4][4][4][MAXL];  // [wid][qs][h][j]
    int wid = threadIdx.x >> 6, lane = threadIdx.x & 63;
    int node = blockIdx.x * 4 + wid;
    if (node >= NNODES) return;
    int st = starts[node];
    int len = cnt[node];
    if (len <= 0) return;
    if (len > MAXL) len = MAXL;
    int qs = lane >> 4, li = lane & 15, h = li >> 2;
    const float scale = 0.17677669529663687f;  // 1/sqrt(32)

    for (int qb = 0; qb < len; qb += 4) {
        int qi = qb + qs;
        bool act = qi < len;
        int qidx = act ? qi : len - 1;
        bf16x8 qv = *reinterpret_cast<const bf16x8*>(
            qkv + (size_t)(st + qidx) * 384 + li * 8);
        float qf[8];
#pragma unroll
        for (int e = 0; e < 8; ++e) qf[e] = b2f(qv[e]);
        // scores
        for (int j = 0; j < len; ++j) {
            bf16x8 kv = *reinterpret_cast<const bf16x8*>(
                qkv + (size_t)(st + j) * 384 + 128 + li * 8);
            float d = 0.f;
#pragma unroll
            for (int e = 0; e < 8; ++e) d += qf[e] * b2f(kv[e]);
            d += __shfl_xor(d, 1, 64);
            d += __shfl_xor(d, 2, 64);
            if ((li & 3) == 0) sc[wid][qs][h][j] = d * scale;
        }
        // softmax: 4 lanes per (qs,h)
        float mx = -1e30f;
        for (int j = li & 3; j < len; j += 4) mx = fmaxf(mx, sc[wid][qs][h][j]);
        mx = fmaxf(mx, __shfl_xor(mx, 1, 64));
        mx = fmaxf(mx, __shfl_xor(mx, 2, 64));
        float ssum = 0.f;
        for (int j = li & 3; j < len; j += 4) {
            float e = __expf(sc[wid][qs][h][j] - mx);
            sc[wid][qs][h][j] = e;
            ssum += e;
        }
        ssum += __shfl_xor(ssum, 1, 64);
        ssum += __shfl_xor(ssum, 2, 64);
        float sinv = 1.f / ssum;
        // PV
        float accv[8] = {0.f, 0.f, 0.f, 0.f, 0.f, 0.f, 0.f, 0.f};
        for (int j = 0; j < len; ++j) {
            float p = sc[wid][qs][h][j];
            bf16x8 vv = *reinterpret_cast<const bf16x8*>(
                qkv + (size_t)(st + j) * 384 + 256 + li * 8);
#pragma unroll
            for (int e = 0; e < 8; ++e) accv[e] += p * b2f(vv[e]);
        }
        if (act) {
            bf16x8 ov;
#pragma unroll
            for (int e = 0; e < 8; ++e) {
                __hip_bfloat16 t = __float2bfloat16(accv[e] * sinv);
                ov[e] = *reinterpret_cast<short*>(&t);
            }
            *reinterpret_cast<bf16x8*>(o + (size_t)(st + qi) * 128 + li * 8) = ov;
        }
    }
}

// ---------------- p1 GEMM + relu + head (logits+softmax) ----------------
__global__ __launch_bounds__(256) void p1head_k(
    const __hip_bfloat16* __restrict__ A, const __hip_bfloat16* __restrict__ B,
    const float* __restrict__ bias, const float* __restrict__ p2w,
    const float* __restrict__ p2b, const int* __restrict__ order,
    float* __restrict__ out) {
    __shared__ __align__(16) char smem[65536];
    __shared__ float p2s[640];
    __shared__ float p2bs[5];
    float4* As4 = (float4*)smem;
    float4* Bs4 = (float4*)(smem + 16384);
    float* rowbuf = (float*)smem;
    int tid = threadIdx.x;
    for (int i = tid; i < 640; i += 256) p2s[i] = p2w[i];
    if (tid < 5) p2bs[tid] = p2b[tid];
    int lane = tid & 63, wid = tid >> 6;
    int wm = wid & 1, wn = wid >> 1;
    int mBase = blockIdx.x * 128;
    f32x4 acc[4][4];
#pragma unroll
    for (int i = 0; i < 4; ++i)
#pragma unroll
        for (int j = 0; j < 4; ++j) {
            f32x4 z = {0.f, 0.f, 0.f, 0.f};
            acc[i][j] = z;
        }
    bf16x8* AsV = reinterpret_cast<bf16x8*>(As4);
    bf16x8* BsV = reinterpret_cast<bf16x8*>(Bs4);
    for (int k0 = 0; k0 < 128; k0 += 64) {
#pragma unroll
        for (int i = 0; i < 4; ++i) {
            int cid = i * 256 + tid;
            int r = cid >> 3, c = cid & 7;
            int sidx = r * 8 + (c ^ (r & 7));
            As4[sidx] = *reinterpret_cast<const float4*>(A + (size_t)(mBase + r) * 128 + k0 + c * 8);
            Bs4[sidx] = *reinterpret_cast<const float4*>(B + (size_t)r * 128 + k0 + c * 8);
        }
        __syncthreads();
#pragma unroll
        for (int kk = 0; kk < 2; ++kk) {
            bf16x8 a[4], bb[4];
            int ccol = kk * 4 + (lane >> 4);
#pragma unroll
            for (int f = 0; f < 4; ++f) {
                int ra = wm * 64 + f * 16 + (lane & 15);
                a[f] = AsV[ra * 8 + (ccol ^ (ra & 7))];
                int rb = wn * 64 + f * 16 + (lane & 15);
                bb[f] = BsV[rb * 8 + (ccol ^ (rb & 7))];
            }
#pragma unroll
            for (int fm = 0; fm < 4; ++fm)
#pragma unroll
                for (int fn = 0; fn < 4; ++fn)
                    acc[fm][fn] = __builtin_amdgcn_mfma_f32_16x16x32_bf16(
                        a[fm], bb[fn], acc[fm][fn], 0, 0, 0);
        }
        __syncthreads();
    }
#pragma unroll
    for (int fm = 0; fm < 4; ++fm) {
        int rl0 = wm * 64 + fm * 16 + (lane >> 4) * 4;
#pragma unroll
        for (int fn = 0; fn < 4; ++fn) {
            int col = wn * 64 + fn * 16 + (lane & 15);
            float bv = bias[col];
#pragma unroll
            for (int j = 0; j < 4; ++j) {
                int rl = rl0 + j;
                rowbuf[rl * 128 + (col ^ ((rl & 7) << 2))] = fmaxf(acc[fm][fn][j] + bv, 0.f);
            }
        }
    }
    __syncthreads();
    int row = tid >> 1, half = tid & 1;
    int swz = (row & 7) << 2;
    float lg[5] = {0.f, 0.f, 0.f, 0.f, 0.f};
    for (int i = 0; i < 64; ++i) {
        int col = half * 64 + i;
        float rv = rowbuf[row * 128 + (col ^ swz)];
#pragma unroll
        for (int k = 0; k < 5; ++k) lg[k] += rv * p2s[k * 128 + col];
    }
#pragma unroll
    for (int k = 0; k < 5; ++k) lg[k] += __shfl_xor(lg[k], 1, 64);
    if (half == 0) {
        float mx = -1e30f;
#pragma unroll
        for (int k = 0; k < 5; ++k) {
            lg[k] += p2bs[k];
            mx = fmaxf(mx, lg[k]);
        }
        float e[5], ssum = 0.f;
#pragma unroll
        for (int k = 0; k < 5; ++k) {
            e[k] = __expf(lg[k] - mx);
            ssum += e[k];
        }
        float si = 1.f / ssum;
        int t = order[mBase + row];
#pragma unroll
        for (int k = 0; k < 5; ++k) out[(size_t)t * 5 + k] = e[k] * si;
    }
}

// ---------------- host launch ----------------

extern "C" void kernel_launch(void* const* d_in, const int* in_sizes, int n_in,
                              void* d_out, int out_size, void* d_ws, size_t ws_size,
                              hipStream_t stream) {
    const int* src = (const int*)d_in[0];
    const int* dst = (const int*)d_in[1];
    const int* neg = (const int*)d_in[2];
    const int* eidx = (const int*)d_in[3];
    const float* ts = (const float*)d_in[4];
    const float* node_feats = (const float*)d_in[5];
    const float* edge_feats = (const float*)d_in[6];
    const float* node_lin_w = (const float*)d_in[7];
    const float* node_lin_b = (const float*)d_in[8];
    const float* edge_lin_w = (const float*)d_in[9];
    const float* edge_lin_b = (const float*)d_in[10];
    const float* time_w = (const float*)d_in[11];
    const float* time_b = (const float*)d_in[12];
    const float* tok_w = (const float*)d_in[13];
    const float* tok_b = (const float*)d_in[14];
    const float* qkv_w = (const float*)d_in[15];
    const float* qkv_b = (const float*)d_in[16];
    const float* attn_w = (const float*)d_in[17];
    const float* attn_b = (const float*)d_in[18];
    const float* ln1_s = (const float*)d_in[19];
    const float* ln1_b = (const float*)d_in[20];
    const float* ln2_s = (const float*)d_in[21];
    const float* ln2_b = (const float*)d_in[22];
    const float* ff1_w = (const float*)d_in[23];
    const float* ff1_b = (const float*)d_in[24];
    const float* ff2_w = (const float*)d_in[25];
    const float* ff2_b = (const float*)d_in[26];
    const float* p1_w = (const float*)d_in[27];
    const float* p1_b = (const float*)d_in[28];
    const float* p2_w = (const float*)d_in[29];
    const float* p2_b = (const float*)d_in[30];
    float* out = (float*)d_out;

    char* w = (char*)d_ws;
    auto alloc = [&](size_t bytes) {
        char* p = w;
        w += (bytes + 255) & ~(size_t)255;
        return p;
    };
    float* x = (float*)alloc((size_t)NTOK * 128 * 4);
    __hip_bfloat16* h = (__hip_bfloat16*)alloc((size_t)NTOK * 128 * 2);
    char* big = alloc((size_t)(NTOK + 64) * 512 * 2);   // qkvb+ob / ub
    __hip_bfloat16* qkvb = (__hip_bfloat16*)big;
    __hip_bfloat16* ob = (__hip_bfloat16*)(big + (size_t)(NTOK + 64) * 384 * 2);
    __hip_bfloat16* ub = (__hip_bfloat16*)big;
    float* P12 = (float*)alloc((size_t)NNODES * 256 * 4);
    float* E = (float*)alloc((size_t)NB * 128 * 4);
    __hip_bfloat16* Aemb = (__hip_bfloat16*)alloc((size_t)NB * 192 * 2);
    __hip_bfloat16* nfb = (__hip_bfloat16*)alloc((size_t)NNODES * 128 * 2);
    __hip_bfloat16* A12 = (__hip_bfloat16*)alloc(256 * 128 * 2);
    __hip_bfloat16* AE = (__hip_bfloat16*)alloc(128 * 192 * 2);
    float* bfold = (float*)alloc(128 * 4);
    __hip_bfloat16* qkvwb = (__hip_bfloat16*)alloc(2 * 384 * 128 * 2);
    __hip_bfloat16* attnwb = (__hip_bfloat16*)alloc(2 * 128 * 128 * 2);
    __hip_bfloat16* ff1wb = (__hip_bfloat16*)alloc(2 * 512 * 128 * 2);
    __hip_bfloat16* ff2wb = (__hip_bfloat16*)alloc(2 * 128 * 512 * 2);
    __hip_bfloat16* p1wb = (__hip_bfloat16*)alloc(128 * 128 * 2);
    int* cnt = (int*)alloc(NNODES * 4);
    int* starts = (int*)alloc(NNODES * 4);
    int* cursor = (int*)alloc(NNODES * 4);
    int* order = (int*)alloc(NTOK * 4);

    hipMemsetAsync(cnt, 0, NNODES * 4, stream);
    hipMemsetAsync(cursor, 0, NNODES * 4, stream);

    auto cvt = [&](const float* in, __hip_bfloat16* outp, int n) {
        int blocks = (n + 255) / 256;
        if (blocks > 2048) blocks = 2048;
        convert_k<<<blocks, 256, 0, stream>>>(in, outp, n);
    };
    cvt(node_feats, nfb, NNODES * 128);
    cvt(qkv_w, qkvwb, 2 * 384 * 128);
    cvt(attn_w, attnwb, 2 * 128 * 128);
    cvt(ff1_w, ff1wb, 2 * 512 * 128);
    cvt(ff2_w, ff2wb, 2 * 128 * 512);
    cvt(p1_w, p1wb, 128 * 128);

    fold12_k<<<128, 256, 0, stream>>>(tok_w, node_lin_w, A12);
    foldE_k<<<96, 256, 0, stream>>>(tok_w, edge_lin_w, AE);
    foldb_k<<<1, 128, 0, stream>>>(tok_w, tok_b, node_lin_b, edge_lin_b, bfold);

    count_k<<<(NTOK + 255) / 256, 256, 0, stream>>>(src, dst, neg, cnt);
    scan_k<<<1, 1024, 0, stream>>>(cnt, starts);
    scatter_k<<<(NTOK + 255) / 256, 256, 0, stream>>>(src, dst, neg, starts, cursor, order);

    aemb_k<<<(NB * 192 + 255) / 256, 256, 0, stream>>>(eidx, ts, edge_feats, time_w, time_b, Aemb);

    gemm_k<<<dim3(157, 2), 256, 0, stream>>>(nfb, A12, nullptr, P12, NNODES, 256, 128);
    gemm_k<<<dim3(256, 1), 256, 0, stream>>>(Aemb, AE, bfold, E, NB, 128, 192);
    asm_emb_k<<<NTOK / 4, 256, 0, stream>>>(order, src, dst, neg, P12, E,
                                            ln1_s, ln1_b, x, h);

    const int gm = NTOK / 128;  // 768
    for (int l = 0; l < 2; ++l) {
        gemm3_k<G2_BF16><<<dim3(gm, 3), 256, 0, stream>>>(
            h, qkvwb + (size_t)l * 384 * 128, qkv_b + l * 384,
            nullptr, nullptr, nullptr, qkvb, 384);
        attn_k<<<(NNODES + 3) / 4, 256, 0, stream>>>(qkvb, starts, cnt, ob);
        gemm3_k<G2_ADD_LN><<<dim3(gm, 1), 256, 0, stream>>>(
            ob, attnwb + (size_t)l * 128 * 128, attn_b + l * 128,
            x, ln2_s + l * 128, ln2_b + l * 128, h, 128);
        gemm3_k<G2_GELU><<<dim3(gm, 4), 256, 0, stream>>>(
            h, ff1wb + (size_t)l * 512 * 128, ff1_b + l * 512,
            nullptr, nullptr, nullptr, ub, 512);
        if (l == 0)
            gemm2_k<G2_ADD_LN><<<dim3(gm, 1), 256, 0, stream>>>(
                ub, ff2wb, ff2_b, x, ln1_s + 128, ln1_b + 128, h, 128, 512);
        else
            gemm2_k<G2_ADD_BF16><<<dim3(gm, 1), 256, 0, stream>>>(
                ub, ff2wb + (size_t)128 * 512, ff2_b + 128, x,
                nullptr, nullptr, h, 128, 512);
    }

    p1head_k<<<gm, 256, 0, stream>>>(h, p1wb, p1_b, p2_w, p2_b, order, out);
}